// Round 1
// baseline (20258.026 us; speedup 1.0000x reference)
//
#include <hip/hip_runtime.h>
#include <math.h>

#define NR 1024

__device__ __forceinline__ float sp100f(float z){
    float x = 100.f*z;
    return (fmaxf(x,0.f) + log1pf(expf(-fabsf(x)))) * 0.01f;
}
__device__ __forceinline__ float sigm(float x){ return 1.f/(1.f+expf(-x)); }

// ---------------- GEMM: C[M,N] = act(A[M,K] @ B (+bias)) ----------------
// TRB=0: B is [K][N] row-major (ldb=N). TRB=1: B is [N][K] row-major (ldb=K), i.e. C=A@B^T.
// ACT: 0 none, 1 softplus(100x)/100, 2 relu, 3 multiply by (1-exp(-100*aux)), 4 sigmoid.
template<int TRB, int ACT>
__global__ __launch_bounds__(256) void k_gemm(
    const float* __restrict__ A, int lda,
    const float* __restrict__ B, int ldb,
    const float* __restrict__ bias,
    const float* __restrict__ aux, int ldaux,
    float* __restrict__ C, int ldc,
    int M, int N, int K)
{
    __shared__ float As[16][68];
    __shared__ float Bs[16][68];
    const int bm = blockIdx.y*64, bn = blockIdx.x*64;
    const int tid = threadIdx.x;
    const int tr = tid>>4, tc = tid&15;
    float acc[4][4] = {};
    for (int k0 = 0; k0 < K; k0 += 16){
        {
            int m = tid>>2, kb = (tid&3)*4;
            int gm = bm+m;
            #pragma unroll
            for (int q=0;q<4;q++){
                int gk = k0+kb+q;
                As[kb+q][m] = (gm<M && gk<K) ? A[(size_t)gm*lda+gk] : 0.f;
            }
        }
        if (TRB){
            int nn = tid>>2, kb=(tid&3)*4;
            int gn = bn+nn;
            #pragma unroll
            for (int q=0;q<4;q++){
                int gk = k0+kb+q;
                Bs[kb+q][nn] = (gn<N && gk<K) ? B[(size_t)gn*ldb+gk] : 0.f;
            }
        } else {
            int kk = tid>>4, nb=(tid&15)*4;
            int gk = k0+kk;
            #pragma unroll
            for (int q=0;q<4;q++){
                int gn = bn+nb+q;
                Bs[kk][nb+q] = (gn<N && gk<K) ? B[(size_t)gk*ldb+gn] : 0.f;
            }
        }
        __syncthreads();
        #pragma unroll
        for (int kk=0;kk<16;kk++){
            float av[4], bv[4];
            #pragma unroll
            for (int i=0;i<4;i++) av[i] = As[kk][tr*4+i];
            #pragma unroll
            for (int j=0;j<4;j++) bv[j] = Bs[kk][tc*4+j];
            #pragma unroll
            for (int i=0;i<4;i++)
                #pragma unroll
                for (int j=0;j<4;j++)
                    acc[i][j] += av[i]*bv[j];
        }
        __syncthreads();
    }
    #pragma unroll
    for (int i=0;i<4;i++){
        int gm = bm+tr*4+i; if (gm>=M) continue;
        #pragma unroll
        for (int j=0;j<4;j++){
            int gn = bn+tc*4+j; if (gn>=N) continue;
            float v = acc[i][j];
            if (ACT!=3 && bias) v += bias[gn];
            if (ACT==1) v = sp100f(v);
            else if (ACT==2) v = fmaxf(v,0.f);
            else if (ACT==3) v = v * (1.f - expf(-100.f*aux[(size_t)gm*ldaux+gn]));
            else if (ACT==4) v = sigm(v);
            C[(size_t)gm*ldc+gn] = v;
        }
    }
}

static inline void run_gemm(hipStream_t s, int trb, int act,
    const float* A,int lda,const float* B,int ldb,const float* bias,
    const float* aux,int ldaux,float* C,int ldc,int M,int N,int K)
{
    dim3 g((N+63)/64,(M+63)/64), b(256);
    #define LNCH(T,Ac) k_gemm<T,Ac><<<g,b,0,s>>>(A,lda,B,ldb,bias,aux,ldaux,C,ldc,M,N,K)
    if (!trb){
        if (act==0) LNCH(0,0); else if (act==1) LNCH(0,1);
        else if (act==2) LNCH(0,2); else LNCH(0,4);
    } else {
        if (act==0) LNCH(1,0); else LNCH(1,3);
    }
    #undef LNCH
}

// ---------------- small kernels ----------------
__global__ void k_ray_setup(const float* __restrict__ o, const float* __restrict__ d,
                            float* __restrict__ z)
{
    int r = blockIdx.x; int i = threadIdx.x; // grid 1024, block 64
    float ox=o[3*r],oy=o[3*r+1],oz=o[3*r+2];
    float dx=d[3*r],dy=d[3*r+1],dz=d[3*r+2];
    float a = dx*dx+dy*dy+dz*dz;
    float b = 2.f*(ox*dx+oy*dy+oz*dz);
    float mid = -b/(2.f*a);
    float nearv = fmaxf(mid-1.f, 0.05f);
    float farv = mid+1.f;
    z[r*128+i] = nearv + (farv-nearv)*((float)i/63.f);
}

__global__ void k_pts(const float* __restrict__ zbuf, int per_ray, int stride,
                      const float* __restrict__ o, const float* __restrict__ d,
                      float* __restrict__ pts, int np)
{
    int i = blockIdx.x*256+threadIdx.x; if (i>=np) return;
    int r = i/per_ray, k = i%per_ray;
    float z = zbuf[r*stride+k];
    pts[3*i+0] = o[3*r+0]+d[3*r+0]*z;
    pts[3*i+1] = o[3*r+1]+d[3*r+1]*z;
    pts[3*i+2] = o[3*r+2]+d[3*r+2]*z;
}

__global__ void k_pts_mid(const float* __restrict__ z, const float* __restrict__ o,
                          const float* __restrict__ d, int off, int n,
                          float* __restrict__ pts)
{
    int i = blockIdx.x*256+threadIdx.x; if (i>=n) return;
    int p = off+i; int r = p>>7; int sI = p&127;
    float zv = z[r*128+sI];
    float dist = (sI<127) ? z[r*128+sI+1]-zv : 0.03125f;
    float mid = zv + 0.5f*dist;
    pts[3*i+0]=o[3*r+0]+d[3*r+0]*mid;
    pts[3*i+1]=o[3*r+1]+d[3*r+1]*mid;
    pts[3*i+2]=o[3*r+2]+d[3*r+2]*mid;
}

__global__ void k_embed(const float* __restrict__ pts, float* __restrict__ e, int n)
{
    int i = blockIdx.x*256+threadIdx.x; if (i>=n) return;
    float p0=pts[3*i],p1=pts[3*i+1],p2=pts[3*i+2];
    float* ei = e + (size_t)i*39;
    ei[0]=p0; ei[1]=p1; ei[2]=p2;
    float f=1.f;
    #pragma unroll
    for (int fq=0; fq<6; fq++){
        ei[3+6*fq+0]=sinf(f*p0); ei[3+6*fq+1]=sinf(f*p1); ei[3+6*fq+2]=sinf(f*p2);
        ei[3+6*fq+3]=cosf(f*p0); ei[3+6*fq+4]=cosf(f*p1); ei[3+6*fq+5]=cosf(f*p2);
        f *= 2.f;
    }
}

__global__ void k_concat(const float* __restrict__ h3, const float* __restrict__ e,
                         float* __restrict__ cin4, int n)
{
    int idx = blockIdx.x*256+threadIdx.x; if (idx>=n*256) return;
    int i = idx>>8, j = idx&255;
    const float IS2 = 0.70710678118654752f;
    cin4[idx] = (j<217 ? h3[(size_t)i*217+j] : e[(size_t)i*39+(j-217)]) * IS2;
}

// sdf[m] = h7[m,:] . W8[:,0] + b8[0], one wave per point
__global__ void k_sdf_tail(const float* __restrict__ h7, const float* __restrict__ W8,
                           const float* __restrict__ b8, float* __restrict__ out,
                           int n, int off, int per_ray, int stride)
{
    int w = (blockIdx.x*blockDim.x+threadIdx.x)>>6;
    int lane = threadIdx.x & 63;
    if (w >= n) return;
    float sacc = 0.f;
    #pragma unroll
    for (int q=0;q<4;q++){
        int k = lane + 64*q;
        sacc += h7[(size_t)w*256+k] * W8[(size_t)k*257];
    }
    #pragma unroll
    for (int m=32;m>=1;m>>=1) sacc += __shfl_xor(sacc, m, 64);
    if (lane==0){
        int p = off + w;
        out[(p/per_ray)*stride + (p%per_ray)] = sacc + b8[0];
    }
}

__global__ void k_copy_sdf(const float* __restrict__ out257, float* __restrict__ sdf_fin,
                           int off, int n)
{
    int i = blockIdx.x*256+threadIdx.x; if (i>=n) return;
    sdf_fin[off+i] = out257[(size_t)i*257];
}

__global__ void k_bwd_init(const float* __restrict__ W8, const float* __restrict__ h7,
                           float* __restrict__ dZ7, int n)
{
    int idx = blockIdx.x*256+threadIdx.x; if (idx>=n*256) return;
    int j = idx&255;
    dZ7[idx] = W8[(size_t)j*257] * (1.f - expf(-100.f*h7[idx]));
}

__global__ void k_split4(const float* __restrict__ din4, const float* __restrict__ h3,
                         float* __restrict__ dZ3, float* __restrict__ de_tail, int n)
{
    int idx = blockIdx.x*256+threadIdx.x; if (idx>=n*256) return;
    int i = idx>>8, j = idx&255;
    const float IS2 = 0.70710678118654752f;
    float v = din4[idx]*IS2;
    if (j<217) dZ3[(size_t)i*217+j] = v * (1.f - expf(-100.f*h3[(size_t)i*217+j]));
    else       de_tail[(size_t)i*39+(j-217)] = v;
}

__global__ void k_fill_feat(const float* __restrict__ out257, float* __restrict__ cin, int n)
{
    int idx = blockIdx.x*256+threadIdx.x; if (idx>=n*256) return;
    int i = idx>>8, j = idx&255;
    cin[(size_t)i*265+9+j] = out257[(size_t)i*257+1+j];
}

__global__ void k_emb_bwd(const float* __restrict__ pts, const float* __restrict__ din0,
                          const float* __restrict__ de_tail, const float* __restrict__ rd,
                          int off, int n, float* __restrict__ cin, float* __restrict__ tcos)
{
    int i = blockIdx.x*256+threadIdx.x; if (i>=n) return;
    int p = off+i; int r = p>>7;
    float px=pts[3*i],py=pts[3*i+1],pz=pts[3*i+2];
    const float* a = din0 + (size_t)i*39;
    const float* b = de_tail + (size_t)i*39;
    float g0=a[0]+b[0], g1=a[1]+b[1], g2=a[2]+b[2];
    float f=1.f;
    #pragma unroll
    for (int fq=0; fq<6; fq++){
        int base = 3+6*fq;
        float ds0=a[base+0]+b[base+0], ds1=a[base+1]+b[base+1], ds2=a[base+2]+b[base+2];
        float dc0=a[base+3]+b[base+3], dc1=a[base+4]+b[base+4], dc2=a[base+5]+b[base+5];
        g0 += f*(cosf(f*px)*ds0 - sinf(f*px)*dc0);
        g1 += f*(cosf(f*py)*ds1 - sinf(f*py)*dc1);
        g2 += f*(cosf(f*pz)*ds2 - sinf(f*pz)*dc2);
        f *= 2.f;
    }
    float dx=rd[3*r],dy=rd[3*r+1],dz=rd[3*r+2];
    tcos[p] = dx*g0+dy*g1+dz*g2;
    float nm = sqrtf(g0*g0+g1*g1+g2*g2);
    nm = fmaxf(nm, 1e-6f);
    float* ci = cin + (size_t)i*265;
    ci[0]=px; ci[1]=py; ci[2]=pz;
    ci[3]=dx; ci[4]=dy; ci[5]=dz;
    ci[6]=g0/nm; ci[7]=g1/nm; ci[8]=g2/nm;
}

__global__ void k_upsample(const float* __restrict__ o, const float* __restrict__ d,
                           const float* __restrict__ z, const float* __restrict__ sdf,
                           int S, float inv_s, float* __restrict__ new_z)
{
    int r = blockIdx.x*64+threadIdx.x; if (r>=NR) return;
    const float* zr = z + r*128;
    const float* sr = sdf + r*128;
    float ox=o[3*r],oy=o[3*r+1],oz=o[3*r+2];
    float dx=d[3*r],dy=d[3*r+1],dz=d[3*r+2];
    float w[128];
    float cdf[129];
    float wsum=0.f, T=1.f, raw_prev=0.f;
    float z0 = zr[0];
    float px=ox+dx*z0, py=oy+dy*z0, pz=oz+dz*z0;
    float r0 = sqrtf(px*px+py*py+pz*pz);
    for (int i=0;i<S-1;i++){
        float z1 = zr[i+1];
        float qx=ox+dx*z1, qy=oy+dy*z1, qz=oz+dz*z1;
        float r1 = sqrtf(qx*qx+qy*qy+qz*qz);
        bool inside = (r0<1.f)||(r1<1.f);
        float s0=sr[i], s1=sr[i+1];
        float zc = zr[i];
        float mid_sdf = 0.5f*(s0+s1);
        float raw = (s1-s0)/(z1-zc+1e-5f);
        float cv = fminf(raw, (i==0)?0.f:raw_prev);
        raw_prev = raw;
        cv = fminf(fmaxf(cv,-1000.f),0.f);
        if (!inside) cv = 0.f;
        float dist = z1-zc;
        float pe = mid_sdf - cv*dist*0.5f;
        float ne = mid_sdf + cv*dist*0.5f;
        float pc = sigm(pe*inv_s), nc = sigm(ne*inv_s);
        float alpha = (pc-nc+1e-5f)/(pc+1e-5f);
        float wi = alpha*T;
        T *= (1.f-alpha+1e-7f);
        w[i] = wi + 1e-5f;
        wsum += w[i];
        r0 = r1;
    }
    cdf[0]=0.f;
    float c=0.f;
    for (int i=0;i<S-1;i++){ c += w[i]/wsum; cdf[i+1]=c; }
    // sample 16 (linspace(0.5/16, 1-0.5/16, 16))
    for (int j=0;j<16;j++){
        float u = 0.03125f + 0.0625f*(float)j;
        int lo=0, hi=S;
        while (lo<hi){ int m=(lo+hi)>>1; if (cdf[m]<=u) lo=m+1; else hi=m; }
        int idx = lo;
        int below = idx-1; if (below<0) below=0; if (below>S-1) below=S-1;
        int above = idx;   if (above>S-1) above=S-1;
        float c0=cdf[below], c1=cdf[above];
        float b0=zr[below], b1=zr[above];
        float dn = c1-c0; if (dn<1e-5f) dn=1.f;
        new_z[r*16+j] = b0 + (u-c0)/dn*(b1-b0);
    }
}

__global__ void k_merge(const float* __restrict__ zin, const float* __restrict__ sin_,
                        const float* __restrict__ nz, const float* __restrict__ nsdf,
                        int S, float* __restrict__ zout, float* __restrict__ sout)
{
    int r = blockIdx.x*64+threadIdx.x; if (r>=NR) return;
    const float* az = zin + r*128; const float* as = sin_ + r*128;
    const float* bz = nz + r*16;   const float* bs = nsdf + r*16;
    int i=0, j=0;
    for (int k=0;k<S+16;k++){
        bool takeA = (j>=16) || (i<S && az[i] <= bz[j]);
        if (takeA){ zout[r*128+k]=az[i]; sout[r*128+k]=as[i]; i++; }
        else      { zout[r*128+k]=bz[j]; sout[r*128+k]=bs[j]; j++; }
    }
}

__global__ void k_composite(const float* __restrict__ z, const float* __restrict__ sdfv,
                            const float* __restrict__ tcos, const float* __restrict__ rgbs,
                            const float* __restrict__ var, float* __restrict__ out)
{
    int r = blockIdx.x*64+threadIdx.x; if (r>=NR) return;
    float inv_s = expf(var[0]*10.f);
    inv_s = fminf(fmaxf(inv_s,1e-6f),1e6f);
    float T=1.f, c0=0.f, c1=0.f, c2=0.f;
    for (int sI=0;sI<128;sI++){
        float zv = z[r*128+sI];
        float dist = (sI<127)? z[r*128+sI+1]-zv : 0.03125f;
        float sd = sdfv[r*128+sI];
        float ic = fminf(tcos[r*128+sI], 0.f);
        float ep = sd - ic*dist*0.5f, en = sd + ic*dist*0.5f;
        float pc = sigm(ep*inv_s), nc = sigm(en*inv_s);
        float al = (pc-nc+1e-5f)/(pc+1e-5f);
        al = fminf(fmaxf(al,0.f),1.f);
        float wgt = al*T;
        T *= (1.f-al+1e-7f);
        c0 += wgt*rgbs[(size_t)(r*128+sI)*3+0];
        c1 += wgt*rgbs[(size_t)(r*128+sI)*3+1];
        c2 += wgt*rgbs[(size_t)(r*128+sI)*3+2];
    }
    out[3*r+0]=c0; out[3*r+1]=c1; out[3*r+2]=c2;
}

// ---------------- host ----------------
static void eval_sdf(hipStream_t s, const float* pts, int np, int CF,
                     float* e, float* b1, float* b2,
                     const float* const* sw, const float* const* sb,
                     float* outbuf, int per_ray, int stride)
{
    for (int off=0; off<np; off+=CF){
        int n = (np-off < CF) ? (np-off) : CF;
        k_embed<<<(n+255)/256,256,0,s>>>(pts+(size_t)off*3, e, n);
        run_gemm(s,0,1, e,39,  sw[0],256, sb[0], nullptr,0, b1,256, n,256,39);
        run_gemm(s,0,1, b1,256, sw[1],256, sb[1], nullptr,0, b2,256, n,256,256);
        run_gemm(s,0,1, b2,256, sw[2],256, sb[2], nullptr,0, b1,256, n,256,256);
        run_gemm(s,0,1, b1,256, sw[3],217, sb[3], nullptr,0, b2,217, n,217,256);
        k_concat<<<(n*256+255)/256,256,0,s>>>(b2, e, b1, n);
        run_gemm(s,0,1, b1,256, sw[4],256, sb[4], nullptr,0, b2,256, n,256,256);
        run_gemm(s,0,1, b2,256, sw[5],256, sb[5], nullptr,0, b1,256, n,256,256);
        run_gemm(s,0,1, b1,256, sw[6],256, sb[6], nullptr,0, b2,256, n,256,256);
        run_gemm(s,0,1, b2,256, sw[7],256, sb[7], nullptr,0, b1,256, n,256,256);
        k_sdf_tail<<<(n*64+255)/256,256,0,s>>>(b1, sw[8], sb[8], outbuf, n, off, per_ray, stride);
    }
}

extern "C" void kernel_launch(void* const* d_in, const int* in_sizes, int n_in,
                              void* d_out, int out_size, void* d_ws, size_t ws_size,
                              hipStream_t stream)
{
    const float* rays_o = (const float*)d_in[0];
    const float* rays_d = (const float*)d_in[1];
    const float* sw[9]; const float* sb[9];
    for (int l=0;l<9;l++){ sw[l]=(const float*)d_in[2+2*l]; sb[l]=(const float*)d_in[3+2*l]; }
    const float* cw0=(const float*)d_in[20]; const float* cb0=(const float*)d_in[21];
    const float* cw1=(const float*)d_in[22]; const float* cb1=(const float*)d_in[23];
    const float* cw2=(const float*)d_in[24]; const float* cb2=(const float*)d_in[25];
    const float* varp=(const float*)d_in[26];
    float* out = (float*)d_out;
    float* ws = (float*)d_ws;

    // persistent arena
    size_t off = 0;
    auto alloc = [&](size_t nf){ float* p = ws+off; off += nf; return p; };
    float* zA   = alloc(NR*128);
    float* zB   = alloc(NR*128);
    float* sA   = alloc(NR*128);
    float* sB   = alloc(NR*128);
    float* nzb  = alloc(NR*16);
    float* nsb  = alloc(NR*16);
    float* sdfF = alloc(NR*128);
    float* tcos = alloc(NR*128);
    float* rgbs = alloc((size_t)NR*128*3);
    float* pts  = alloc((size_t)65536*3);
    float* scratch = ws + off;
    size_t avail = ws_size/sizeof(float) > off ? ws_size/sizeof(float) - off : 0;

    int CHF = 8192;
    while (CHF > 1024 && (size_t)CHF*3458 > avail) CHF >>= 1;
    int CF = 16384;
    while (CF > 1024 && (size_t)CF*551 > avail) CF >>= 1;

    // forward-phase scratch (overlaid)
    float* fe = scratch;
    float* fb1 = fe + (size_t)CF*39;
    float* fb2 = fb1 + (size_t)CF*256;

    // 1) rays + base z
    k_ray_setup<<<NR,64,0,stream>>>(rays_o, rays_d, zA);
    // 2) base sdf (64 samples)
    k_pts<<<(65536+255)/256,256,0,stream>>>(zA, 64, 128, rays_o, rays_d, pts, 65536);
    eval_sdf(stream, pts, 65536, CF, fe, fb1, fb2, sw, sb, sA, 64, 128);
    // 3) 4 up-sample steps
    for (int it=0; it<4; it++){
        int S = 64 + 16*it;
        float* zsrc = (it&1)? zB : zA;  float* ssrc = (it&1)? sB : sA;
        float* zdst = (it&1)? zA : zB;  float* sdst = (it&1)? sA : sB;
        float inv_s = 64.f * (float)(1<<it);
        k_upsample<<<NR/64,64,0,stream>>>(rays_o, rays_d, zsrc, ssrc, S, inv_s, nzb);
        k_pts<<<(NR*16+255)/256,256,0,stream>>>(nzb, 16, 16, rays_o, rays_d, pts, NR*16);
        eval_sdf(stream, pts, NR*16, CF, fe, fb1, fb2, sw, sb, nsb, 16, 16);
        k_merge<<<NR/64,64,0,stream>>>(zsrc, ssrc, nzb, nsb, S, zdst, sdst);
    }
    // final z in zA (4 merges: A->B->A->B->A)

    // final-phase scratch (overlaid on same region)
    {
        float* p = scratch;
        float* ptsl  = p; p += (size_t)CHF*3;
        float* e     = p; p += (size_t)CHF*39;
        float* h[8];
        for (int l=0;l<8;l++){ h[l]=p; p += (size_t)CHF*256; }
        float* cin4  = p; p += (size_t)CHF*256;
        float* out257= p; p += (size_t)CHF*257;
        float* g1    = p; p += (size_t)CHF*256;
        float* g2    = p; p += (size_t)CHF*256;
        float* detl  = p; p += (size_t)CHF*39;
        float* din0  = p; p += (size_t)CHF*39;
        float* cin   = p; p += (size_t)CHF*265;

        for (int offp=0; offp<NR*128; offp+=CHF){
            int n = (NR*128-offp < CHF) ? (NR*128-offp) : CHF;
            dim3 gb1((n+255)/256), gb256((n*256+255)/256), b(256);
            k_pts_mid<<<gb1,b,0,stream>>>(zA, rays_o, rays_d, offp, n, ptsl);
            k_embed<<<gb1,b,0,stream>>>(ptsl, e, n);
            // forward with stored activations
            run_gemm(stream,0,1, e,39,   sw[0],256, sb[0], nullptr,0, h[0],256, n,256,39);
            run_gemm(stream,0,1, h[0],256, sw[1],256, sb[1], nullptr,0, h[1],256, n,256,256);
            run_gemm(stream,0,1, h[1],256, sw[2],256, sb[2], nullptr,0, h[2],256, n,256,256);
            run_gemm(stream,0,1, h[2],256, sw[3],217, sb[3], nullptr,0, h[3],217, n,217,256);
            k_concat<<<gb256,b,0,stream>>>(h[3], e, cin4, n);
            run_gemm(stream,0,1, cin4,256, sw[4],256, sb[4], nullptr,0, h[4],256, n,256,256);
            run_gemm(stream,0,1, h[4],256, sw[5],256, sb[5], nullptr,0, h[5],256, n,256,256);
            run_gemm(stream,0,1, h[5],256, sw[6],256, sb[6], nullptr,0, h[6],256, n,256,256);
            run_gemm(stream,0,1, h[6],256, sw[7],256, sb[7], nullptr,0, h[7],256, n,256,256);
            run_gemm(stream,0,0, h[7],256, sw[8],257, sb[8], nullptr,0, out257,257, n,257,256);
            k_copy_sdf<<<gb1,b,0,stream>>>(out257, sdfF, offp, n);
            // backward (sdf wrt pts)
            k_bwd_init<<<gb256,b,0,stream>>>(sw[8], h[7], g1, n);
            run_gemm(stream,1,3, g1,256, sw[7],256, nullptr, h[6],256, g2,256, n,256,256); // dZ6
            run_gemm(stream,1,3, g2,256, sw[6],256, nullptr, h[5],256, g1,256, n,256,256); // dZ5
            run_gemm(stream,1,3, g1,256, sw[5],256, nullptr, h[4],256, g2,256, n,256,256); // dZ4
            run_gemm(stream,1,0, g2,256, sw[4],256, nullptr, nullptr,0, g1,256, n,256,256); // din4
            k_split4<<<gb256,b,0,stream>>>(g1, h[3], g2, detl, n); // g2 = dZ3 (217-wide)
            run_gemm(stream,1,3, g2,217, sw[3],217, nullptr, h[2],256, g1,256, n,256,217); // dZ2
            run_gemm(stream,1,3, g1,256, sw[2],256, nullptr, h[1],256, g2,256, n,256,256); // dZ1
            run_gemm(stream,1,3, g2,256, sw[1],256, nullptr, h[0],256, g1,256, n,256,256); // dZ0
            run_gemm(stream,1,0, g1,256, sw[0],256, nullptr, nullptr,0, din0,39, n,39,256);
            k_emb_bwd<<<gb1,b,0,stream>>>(ptsl, din0, detl, rays_d, offp, n, cin, tcos);
            k_fill_feat<<<gb256,b,0,stream>>>(out257, cin, n);
            // color MLP
            run_gemm(stream,0,2, cin,265, cw0,256, cb0, nullptr,0, g1,256, n,256,265);
            run_gemm(stream,0,2, g1,256,  cw1,256, cb1, nullptr,0, g2,256, n,256,256);
            run_gemm(stream,0,4, g2,256,  cw2,3,   cb2, nullptr,0, rgbs+(size_t)offp*3,3, n,3,256);
        }
    }
    // composite
    k_composite<<<NR/64,64,0,stream>>>(zA, sdfF, tcos, rgbs, varp, out);
}

// Round 2
// 9177.605 us; speedup vs baseline: 2.2073x; 2.2073x over previous
//
#include <hip/hip_runtime.h>
#include <math.h>

#define NR 1024

typedef __bf16 bf16;
typedef bf16 bf16x8 __attribute__((ext_vector_type(8)));
typedef float floatx4 __attribute__((ext_vector_type(4)));

__device__ __forceinline__ float sp100f(float z){
    float x = 100.f*z;
    return (fmaxf(x,0.f) + log1pf(expf(-fabsf(x)))) * 0.01f;
}
__device__ __forceinline__ float sigm(float x){ return 1.f/(1.f+expf(-x)); }

// ============ bf16x3 MFMA GEMM: C[M,N] = act(A[M,K] @ B[N,K]^T + bias) ============
// A given as hi/lo bf16 planes [M][lda]; B given as hi(/lo) planes [N][ldb].
// ACT: 0 none, 1 softplus(100x)/100 (+optional fac=sigmoid(100x) out),
//      2 relu, 3 multiply by bf16 fac input, 5 sdf/feat special (L8).
// PASSES: 3 = AhBh+AhBl+AlBh (forward), 2 = AhBh+AlBh (backward, B hi only).
struct GArgs {
    const bf16 *Ah, *Al; int lda;
    const bf16 *Bh, *Bl; int ldb;
    const float* bias;
    const bf16* fac; int ldfac;
    float* Cf; int ldcf;
    bf16 *Ch, *Cl; int ldc;
    bf16 *Cfac; int ldcfac;
    float* sdfo;
    int M, N, K;
};

template<int ACT, int PASSES>
__global__ __launch_bounds__(256) void k_mgemm(GArgs g)
{
    __shared__ bf16 AsH[128*40];
    __shared__ bf16 AsL[128*40];
    __shared__ bf16 BsH[64*40];
    __shared__ bf16 BsL[(PASSES==3)?64*40:8];
    const int bm = blockIdx.y*128, bn = blockIdx.x*64;
    const int tid = threadIdx.x;
    const int wid = tid>>6, lane = tid&63;
    const int lr = lane&15, lq = lane>>4;
    floatx4 acc[2][4] = {};
    const int nk = (g.K+31)>>5;
    for (int kt=0; kt<nk; kt++){
        const int k0 = kt<<5;
        // stage A: 2 planes x 128 rows x 4 slots of 8 bf16
        #pragma unroll
        for (int c=0;c<4;c++){
            int cid = c*256 + tid;
            int pl = cid>>9, rem = cid&511;
            int row = rem>>2, q = rem&3;
            int gm = bm+row, ks = k0+q*8;
            const bf16* src = pl? g.Al : g.Ah;
            bf16* dst = (pl? AsL : AsH) + row*40 + q*8;
            bf16x8 v;
            if (gm < g.M && ks+8 <= g.K){
                v = *(const bf16x8*)(src + (size_t)gm*g.lda + ks);
            } else {
                #pragma unroll
                for (int j=0;j<8;j++) v[j] = (gm<g.M && ks+j<g.K)? src[(size_t)gm*g.lda+ks+j] : (bf16)0.f;
            }
            *(bf16x8*)dst = v;
        }
        // stage B
        #pragma unroll
        for (int c=0;c<((PASSES==3)?2:1);c++){
            int cid = c*256 + tid;
            int pl = cid>>8, rem = cid&255;
            int row = rem>>2, q = rem&3;
            int gn = bn+row, ks = k0+q*8;
            const bf16* src = pl? g.Bl : g.Bh;
            bf16* dst = (pl? BsL : BsH) + row*40 + q*8;
            bf16x8 v;
            if (gn < g.N && ks+8 <= g.K){
                v = *(const bf16x8*)(src + (size_t)gn*g.ldb + ks);
            } else {
                #pragma unroll
                for (int j=0;j<8;j++) v[j] = (gn<g.N && ks+j<g.K)? src[(size_t)gn*g.ldb+ks+j] : (bf16)0.f;
            }
            *(bf16x8*)dst = v;
        }
        __syncthreads();
        const int ab = (wid*32 + lr)*40 + lq*8;
        bf16x8 a0h = *(const bf16x8*)&AsH[ab];
        bf16x8 a1h = *(const bf16x8*)&AsH[ab+16*40];
        bf16x8 a0l = *(const bf16x8*)&AsL[ab];
        bf16x8 a1l = *(const bf16x8*)&AsL[ab+16*40];
        #pragma unroll
        for (int j=0;j<4;j++){
            int bo = (j*16+lr)*40 + lq*8;
            bf16x8 bh = *(const bf16x8*)&BsH[bo];
            acc[0][j] = __builtin_amdgcn_mfma_f32_16x16x32_bf16(a0h, bh, acc[0][j], 0,0,0);
            acc[1][j] = __builtin_amdgcn_mfma_f32_16x16x32_bf16(a1h, bh, acc[1][j], 0,0,0);
            acc[0][j] = __builtin_amdgcn_mfma_f32_16x16x32_bf16(a0l, bh, acc[0][j], 0,0,0);
            acc[1][j] = __builtin_amdgcn_mfma_f32_16x16x32_bf16(a1l, bh, acc[1][j], 0,0,0);
            if (PASSES==3){
                bf16x8 bl = *(const bf16x8*)&BsL[bo];
                acc[0][j] = __builtin_amdgcn_mfma_f32_16x16x32_bf16(a0h, bl, acc[0][j], 0,0,0);
                acc[1][j] = __builtin_amdgcn_mfma_f32_16x16x32_bf16(a1h, bl, acc[1][j], 0,0,0);
            }
        }
        __syncthreads();
    }
    // epilogue
    #pragma unroll
    for (int i=0;i<2;i++){
        int rbase = bm + wid*32 + i*16 + lq*4;
        #pragma unroll
        for (int j=0;j<4;j++){
            int col = bn + j*16 + lr;
            if (col >= g.N) continue;
            float bv = g.bias ? g.bias[col] : 0.f;
            #pragma unroll
            for (int r=0;r<4;r++){
                int gm = rbase + r;
                if (gm >= g.M) continue;
                float v = acc[i][j][r] + bv;
                if (ACT==1){
                    if (g.Cfac) g.Cfac[(size_t)gm*g.ldcfac + col] = (bf16)sigm(100.f*v);
                    v = sp100f(v);
                } else if (ACT==2){ v = fmaxf(v,0.f); }
                else if (ACT==3){ v *= (float)g.fac[(size_t)gm*g.ldfac + col]; }
                else if (ACT==5){
                    if (col==0){ g.sdfo[gm] = v; continue; }
                    int cc = col + 8;
                    bf16 h = (bf16)v;
                    g.Ch[(size_t)gm*g.ldc + cc] = h;
                    g.Cl[(size_t)gm*g.ldc + cc] = (bf16)(v - (float)h);
                    continue;
                }
                if (g.Cf) g.Cf[(size_t)gm*g.ldcf + col] = v;
                if (g.Ch){
                    bf16 h = (bf16)v;
                    g.Ch[(size_t)gm*g.ldc + col] = h;
                    g.Cl[(size_t)gm*g.ldc + col] = (bf16)(v - (float)h);
                }
            }
        }
    }
}

static void mg(hipStream_t s, int act, GArgs& g){
    dim3 gr((g.N+63)/64,(g.M+127)/128), b(256);
    if (act==1)      k_mgemm<1,3><<<gr,b,0,s>>>(g);
    else if (act==5) k_mgemm<5,3><<<gr,b,0,s>>>(g);
    else if (act==2) k_mgemm<2,3><<<gr,b,0,s>>>(g);
    else if (act==3) k_mgemm<3,2><<<gr,b,0,s>>>(g);
    else             k_mgemm<0,2><<<gr,b,0,s>>>(g);
}

// ============ weight conversion: fp32 W[K][N] -> Wt hi/lo [N][ldt], Wn hi [K][ldn] ============
struct ConvDesc { const float* src; bf16 *th, *tl, *nh; int K, N, ldt, ldn; };
struct ConvArgs { ConvDesc d[11]; };
__global__ void k_conv(ConvArgs a){
    ConvDesc cd = a.d[blockIdx.y];
    int idx = blockIdx.x*256+threadIdx.x;
    if (idx >= cd.K*cd.N) return;
    int k = idx / cd.N, n = idx - k*cd.N;
    float v = cd.src[idx];
    bf16 h = (bf16)v;
    cd.th[(size_t)n*cd.ldt + k] = h;
    cd.tl[(size_t)n*cd.ldt + k] = (bf16)(v - (float)h);
    if (cd.nh) cd.nh[(size_t)k*cd.ldn + n] = h;
}

// ============ small kernels ============
__global__ void k_ray_setup(const float* __restrict__ o, const float* __restrict__ d,
                            float* __restrict__ z)
{
    int r = blockIdx.x; int i = threadIdx.x;
    float ox=o[3*r],oy=o[3*r+1],oz=o[3*r+2];
    float dx=d[3*r],dy=d[3*r+1],dz=d[3*r+2];
    float a = dx*dx+dy*dy+dz*dz;
    float b = 2.f*(ox*dx+oy*dy+oz*dz);
    float mid = -b/(2.f*a);
    float nearv = fmaxf(mid-1.f, 0.05f);
    float farv = mid+1.f;
    z[r*128+i] = nearv + (farv-nearv)*((float)i/63.f);
}

__global__ void k_pts(const float* __restrict__ zbuf, int per_ray, int stride,
                      const float* __restrict__ o, const float* __restrict__ d,
                      float* __restrict__ pts, int np)
{
    int i = blockIdx.x*256+threadIdx.x; if (i>=np) return;
    int r = i/per_ray, k = i%per_ray;
    float z = zbuf[r*stride+k];
    pts[3*i+0] = o[3*r+0]+d[3*r+0]*z;
    pts[3*i+1] = o[3*r+1]+d[3*r+1]*z;
    pts[3*i+2] = o[3*r+2]+d[3*r+2]*z;
}

__global__ void k_pts_mid(const float* __restrict__ z, const float* __restrict__ o,
                          const float* __restrict__ d, int off, int n,
                          float* __restrict__ pts)
{
    int i = blockIdx.x*256+threadIdx.x; if (i>=n) return;
    int p = off+i; int r = p>>7; int sI = p&127;
    float zv = z[r*128+sI];
    float dist = (sI<127) ? z[r*128+sI+1]-zv : 0.03125f;
    float mid = zv + 0.5f*dist;
    pts[3*i+0]=o[3*r+0]+d[3*r+0]*mid;
    pts[3*i+1]=o[3*r+1]+d[3*r+1]*mid;
    pts[3*i+2]=o[3*r+2]+d[3*r+2]*mid;
}

__global__ void k_embed(const float* __restrict__ pts, float* __restrict__ e,
                        bf16* __restrict__ eh, bf16* __restrict__ el, int n)
{
    int i = blockIdx.x*256+threadIdx.x; if (i>=n) return;
    float p0=pts[3*i],p1=pts[3*i+1],p2=pts[3*i+2];
    float* ei = e + (size_t)i*39;
    bf16* hh = eh + (size_t)i*40;
    bf16* ll = el + (size_t)i*40;
    float vals[39];
    vals[0]=p0; vals[1]=p1; vals[2]=p2;
    float f=1.f;
    #pragma unroll
    for (int fq=0; fq<6; fq++){
        vals[3+6*fq+0]=sinf(f*p0); vals[3+6*fq+1]=sinf(f*p1); vals[3+6*fq+2]=sinf(f*p2);
        vals[3+6*fq+3]=cosf(f*p0); vals[3+6*fq+4]=cosf(f*p1); vals[3+6*fq+5]=cosf(f*p2);
        f *= 2.f;
    }
    #pragma unroll
    for (int j=0;j<39;j++){
        float v = vals[j];
        ei[j]=v;
        bf16 h=(bf16)v;
        hh[j]=h; ll[j]=(bf16)(v-(float)h);
    }
}

__global__ void k_concat(const float* __restrict__ h3, const float* __restrict__ e,
                         bf16* __restrict__ ch, bf16* __restrict__ cl, int n)
{
    int idx = blockIdx.x*256+threadIdx.x; if (idx>=n*256) return;
    int i = idx>>8, j = idx&255;
    const float IS2 = 0.70710678118654752f;
    float v = (j<217 ? h3[(size_t)i*217+j] : e[(size_t)i*39+(j-217)]) * IS2;
    bf16 h=(bf16)v;
    ch[idx]=h; cl[idx]=(bf16)(v-(float)h);
}

__global__ void k_sdf_tail(const float* __restrict__ h7, const float* __restrict__ W8,
                           const float* __restrict__ b8, float* __restrict__ out,
                           int n, int off, int per_ray, int stride)
{
    int w = (blockIdx.x*blockDim.x+threadIdx.x)>>6;
    int lane = threadIdx.x & 63;
    if (w >= n) return;
    float sacc = 0.f;
    #pragma unroll
    for (int q=0;q<4;q++){
        int k = lane + 64*q;
        sacc += h7[(size_t)w*256+k] * W8[(size_t)k*257];
    }
    #pragma unroll
    for (int m=32;m>=1;m>>=1) sacc += __shfl_xor(sacc, m, 64);
    if (lane==0){
        int p = off + w;
        out[(p/per_ray)*stride + (p%per_ray)] = sacc + b8[0];
    }
}

__global__ void k_bwd_init(const float* __restrict__ W8, const bf16* __restrict__ fac7,
                           bf16* __restrict__ ch, bf16* __restrict__ cl, int n)
{
    int idx = blockIdx.x*256+threadIdx.x; if (idx>=n*256) return;
    int j = idx&255;
    float v = W8[(size_t)j*257] * (float)fac7[idx];
    bf16 h=(bf16)v;
    ch[idx]=h; cl[idx]=(bf16)(v-(float)h);
}

__global__ void k_split4(const float* __restrict__ din4, const bf16* __restrict__ fac3,
                         bf16* __restrict__ ch, bf16* __restrict__ cl,
                         float* __restrict__ detl, int n)
{
    int idx = blockIdx.x*256+threadIdx.x; if (idx>=n*256) return;
    int i = idx>>8, j = idx&255;
    const float IS2 = 0.70710678118654752f;
    float v = din4[idx]*IS2;
    if (j<217){
        v *= (float)fac3[(size_t)i*217+j];
        bf16 h=(bf16)v;
        ch[(size_t)i*256+j]=h; cl[(size_t)i*256+j]=(bf16)(v-(float)h);
    } else detl[(size_t)i*39+(j-217)] = v;
}

__global__ void k_emb_bwd(const float* __restrict__ pts, const float* __restrict__ din0,
                          const float* __restrict__ de_tail, const float* __restrict__ rd,
                          int off, int n, bf16* __restrict__ ch, bf16* __restrict__ cl,
                          float* __restrict__ tcos)
{
    int i = blockIdx.x*256+threadIdx.x; if (i>=n) return;
    int p = off+i; int r = p>>7;
    float px=pts[3*i],py=pts[3*i+1],pz=pts[3*i+2];
    const float* a = din0 + (size_t)i*39;
    const float* b = de_tail + (size_t)i*39;
    float g0=a[0]+b[0], g1=a[1]+b[1], g2=a[2]+b[2];
    float f=1.f;
    #pragma unroll
    for (int fq=0; fq<6; fq++){
        int base = 3+6*fq;
        float ds0=a[base+0]+b[base+0], ds1=a[base+1]+b[base+1], ds2=a[base+2]+b[base+2];
        float dc0=a[base+3]+b[base+3], dc1=a[base+4]+b[base+4], dc2=a[base+5]+b[base+5];
        g0 += f*(cosf(f*px)*ds0 - sinf(f*px)*dc0);
        g1 += f*(cosf(f*py)*ds1 - sinf(f*py)*dc1);
        g2 += f*(cosf(f*pz)*ds2 - sinf(f*pz)*dc2);
        f *= 2.f;
    }
    float dx=rd[3*r],dy=rd[3*r+1],dz=rd[3*r+2];
    tcos[p] = dx*g0+dy*g1+dz*g2;
    float nm = sqrtf(g0*g0+g1*g1+g2*g2);
    nm = fmaxf(nm, 1e-6f);
    float vals[9] = {px,py,pz,dx,dy,dz,g0/nm,g1/nm,g2/nm};
    bf16* hh = ch + (size_t)i*272;
    bf16* ll = cl + (size_t)i*272;
    #pragma unroll
    for (int c=0;c<9;c++){
        float v = vals[c];
        bf16 h=(bf16)v;
        hh[c]=h; ll[c]=(bf16)(v-(float)h);
    }
}

__global__ void k_rgb(const float* __restrict__ hc, const float* __restrict__ W,
                      const float* __restrict__ b, float* __restrict__ rgb, int n)
{
    int w = (blockIdx.x*blockDim.x+threadIdx.x)>>6;
    int lane = threadIdx.x & 63;
    if (w >= n) return;
    float a0=0.f,a1=0.f,a2=0.f;
    #pragma unroll
    for (int q=0;q<4;q++){
        int k = lane + 64*q;
        float h = hc[(size_t)w*256+k];
        a0 += h*W[k*3]; a1 += h*W[k*3+1]; a2 += h*W[k*3+2];
    }
    #pragma unroll
    for (int m=32;m>=1;m>>=1){
        a0+=__shfl_xor(a0,m,64); a1+=__shfl_xor(a1,m,64); a2+=__shfl_xor(a2,m,64);
    }
    if (lane==0){
        rgb[(size_t)w*3+0]=sigm(a0+b[0]);
        rgb[(size_t)w*3+1]=sigm(a1+b[1]);
        rgb[(size_t)w*3+2]=sigm(a2+b[2]);
    }
}

__global__ void k_upsample(const float* __restrict__ o, const float* __restrict__ d,
                           const float* __restrict__ z, const float* __restrict__ sdf,
                           int S, float inv_s, float* __restrict__ new_z)
{
    int r = blockIdx.x*64+threadIdx.x; if (r>=NR) return;
    const float* zr = z + r*128;
    const float* sr = sdf + r*128;
    float ox=o[3*r],oy=o[3*r+1],oz=o[3*r+2];
    float dx=d[3*r],dy=d[3*r+1],dz=d[3*r+2];
    float w[128];
    float cdf[129];
    float wsum=0.f, T=1.f, raw_prev=0.f;
    float z0 = zr[0];
    float px=ox+dx*z0, py=oy+dy*z0, pz=oz+dz*z0;
    float r0 = sqrtf(px*px+py*py+pz*pz);
    for (int i=0;i<S-1;i++){
        float z1 = zr[i+1];
        float qx=ox+dx*z1, qy=oy+dy*z1, qz=oz+dz*z1;
        float r1 = sqrtf(qx*qx+qy*qy+qz*qz);
        bool inside = (r0<1.f)||(r1<1.f);
        float s0=sr[i], s1=sr[i+1];
        float zc = zr[i];
        float mid_sdf = 0.5f*(s0+s1);
        float raw = (s1-s0)/(z1-zc+1e-5f);
        float cv = fminf(raw, (i==0)?0.f:raw_prev);
        raw_prev = raw;
        cv = fminf(fmaxf(cv,-1000.f),0.f);
        if (!inside) cv = 0.f;
        float dist = z1-zc;
        float pe = mid_sdf - cv*dist*0.5f;
        float ne = mid_sdf + cv*dist*0.5f;
        float pc = sigm(pe*inv_s), nc = sigm(ne*inv_s);
        float alpha = (pc-nc+1e-5f)/(pc+1e-5f);
        float wi = alpha*T;
        T *= (1.f-alpha+1e-7f);
        w[i] = wi + 1e-5f;
        wsum += w[i];
        r0 = r1;
    }
    cdf[0]=0.f;
    float c=0.f;
    for (int i=0;i<S-1;i++){ c += w[i]/wsum; cdf[i+1]=c; }
    for (int j=0;j<16;j++){
        float u = 0.03125f + 0.0625f*(float)j;
        int lo=0, hi=S;
        while (lo<hi){ int m=(lo+hi)>>1; if (cdf[m]<=u) lo=m+1; else hi=m; }
        int idx = lo;
        int below = idx-1; if (below<0) below=0; if (below>S-1) below=S-1;
        int above = idx;   if (above>S-1) above=S-1;
        float c0=cdf[below], c1=cdf[above];
        float b0=zr[below], b1=zr[above];
        float dn = c1-c0; if (dn<1e-5f) dn=1.f;
        new_z[r*16+j] = b0 + (u-c0)/dn*(b1-b0);
    }
}

__global__ void k_merge(const float* __restrict__ zin, const float* __restrict__ sin_,
                        const float* __restrict__ nz, const float* __restrict__ nsdf,
                        int S, float* __restrict__ zout, float* __restrict__ sout)
{
    int r = blockIdx.x*64+threadIdx.x; if (r>=NR) return;
    const float* az = zin + r*128; const float* as = sin_ + r*128;
    const float* bz = nz + r*16;   const float* bs = nsdf + r*16;
    int i=0, j=0;
    for (int k=0;k<S+16;k++){
        bool takeA = (j>=16) || (i<S && az[i] <= bz[j]);
        if (takeA){ zout[r*128+k]=az[i]; sout[r*128+k]=as[i]; i++; }
        else      { zout[r*128+k]=bz[j]; sout[r*128+k]=bs[j]; j++; }
    }
}

__global__ void k_composite(const float* __restrict__ z, const float* __restrict__ sdfv,
                            const float* __restrict__ tcos, const float* __restrict__ rgbs,
                            const float* __restrict__ var, float* __restrict__ out)
{
    int r = blockIdx.x*64+threadIdx.x; if (r>=NR) return;
    float inv_s = expf(var[0]*10.f);
    inv_s = fminf(fmaxf(inv_s,1e-6f),1e6f);
    float T=1.f, c0=0.f, c1=0.f, c2=0.f;
    for (int sI=0;sI<128;sI++){
        float zv = z[r*128+sI];
        float dist = (sI<127)? z[r*128+sI+1]-zv : 0.03125f;
        float sd = sdfv[r*128+sI];
        float ic = fminf(tcos[r*128+sI], 0.f);
        float ep = sd - ic*dist*0.5f, en = sd + ic*dist*0.5f;
        float pc = sigm(ep*inv_s), nc = sigm(en*inv_s);
        float al = (pc-nc+1e-5f)/(pc+1e-5f);
        al = fminf(fmaxf(al,0.f),1.f);
        float wgt = al*T;
        T *= (1.f-al+1e-7f);
        c0 += wgt*rgbs[(size_t)(r*128+sI)*3+0];
        c1 += wgt*rgbs[(size_t)(r*128+sI)*3+1];
        c2 += wgt*rgbs[(size_t)(r*128+sI)*3+2];
    }
    out[3*r+0]=c0; out[3*r+1]=c1; out[3*r+2]=c2;
}

// ============ host ============
static inline size_t ru8(size_t x){ return (x+7)&~(size_t)7; }

struct WPs {
    const bf16 *tH[11], *tL[11]; int ldt[11];
    const bf16 *nH[8]; int ldn[8];
};

extern "C" void kernel_launch(void* const* d_in, const int* in_sizes, int n_in,
                              void* d_out, int out_size, void* d_ws, size_t ws_size,
                              hipStream_t stream)
{
    const float* rays_o = (const float*)d_in[0];
    const float* rays_d = (const float*)d_in[1];
    const float* sw[9]; const float* sb[9];
    for (int l=0;l<9;l++){ sw[l]=(const float*)d_in[2+2*l]; sb[l]=(const float*)d_in[3+2*l]; }
    const float* cw0=(const float*)d_in[20]; const float* cb0=(const float*)d_in[21];
    const float* cw1=(const float*)d_in[22]; const float* cb1=(const float*)d_in[23];
    const float* cw2=(const float*)d_in[24]; const float* cb2=(const float*)d_in[25];
    const float* varp=(const float*)d_in[26];
    float* out = (float*)d_out;
    float* f = (float*)d_ws;
    size_t nf = ws_size/sizeof(float);

    size_t off = 0;
    auto AF = [&](size_t n){ float* p = f+off; off += n; return p; };
    float* zA   = AF(NR*128);
    float* zB   = AF(NR*128);
    float* sA   = AF(NR*128);
    float* sB   = AF(NR*128);
    float* nzb  = AF(NR*16);
    float* nsb  = AF(NR*16);
    float* sdfF = AF(NR*128);
    float* tcos = AF(NR*128);
    float* rgbs = AF((size_t)NR*128*3);
    float* pts  = AF((size_t)65536*3);

    // weight plane pool (bf16)
    bf16* wb = (bf16*)(f+off);
    size_t wboff = 0;
    auto AB = [&](size_t n){ n = ru8(n); bf16* p = wb+wboff; wboff += n; return p; };

    const int inD[9]  = {39,256,256,256,256,256,256,256,256};
    const int outD[9] = {256,256,256,217,256,256,256,256,257};
    WPs wp;
    ConvArgs ca;
    for (int l=0;l<9;l++){
        int K=inD[l], N=outD[l];
        int ldt = (int)ru8(K);
        bf16* th = AB((size_t)N*ldt);
        bf16* tl = AB((size_t)N*ldt);
        bf16* nh = nullptr; int ldn = 0;
        if (l<8){ ldn = (int)ru8(N); nh = AB((size_t)K*ldn); wp.nH[l]=nh; wp.ldn[l]=ldn; }
        wp.tH[l]=th; wp.tL[l]=tl; wp.ldt[l]=ldt;
        ca.d[l] = ConvDesc{ sw[l], th, tl, nh, K, N, ldt, ldn };
    }
    { // cw0: [265][256], cw1: [256][256]
        int K=265, N=256, ldt=(int)ru8(K);
        bf16* th = AB((size_t)N*ldt); bf16* tl = AB((size_t)N*ldt);
        wp.tH[9]=th; wp.tL[9]=tl; wp.ldt[9]=ldt;
        ca.d[9] = ConvDesc{ cw0, th, tl, nullptr, K, N, ldt, 0 };
        K=256; N=256; ldt=256;
        bf16* th1 = AB((size_t)N*ldt); bf16* tl1 = AB((size_t)N*ldt);
        wp.tH[10]=th1; wp.tL[10]=tl1; wp.ldt[10]=ldt;
        ca.d[10] = ConvDesc{ cw1, th1, tl1, nullptr, K, N, ldt, 0 };
    }
    off += (wboff+1)/2;
    float* scratch = f + off;
    size_t avail = (nf > off) ? nf - off : 0;

    // chunk sizes
    int CHF = 16384;
    while (CHF > 1024 && (size_t)CHF*2680 > avail) CHF >>= 1;
    int CF = 16384;
    while (CF > 1024 && (size_t)CF*1330 > avail) CF >>= 1;

    // ---- weight conversion ----
    k_conv<<<dim3(266,11),256,0,stream>>>(ca);

    // ---- rays + base z ----
    k_ray_setup<<<NR,64,0,stream>>>(rays_o, rays_d, zA);
    k_pts<<<(65536+255)/256,256,0,stream>>>(zA, 64, 128, rays_o, rays_d, pts, 65536);

    // ---- sampling-phase buffers (overlay on scratch) ----
    {
        size_t o2 = 0;
        auto F2=[&](size_t n){ float* p=scratch+o2; o2+=n; return p; };
        float* sE  = F2((size_t)39*CF);
        float* sH3 = F2((size_t)217*CF);
        float* sH7 = F2((size_t)256*CF);
        bf16* bb = (bf16*)(scratch+o2);
        size_t bo=0;
        auto B2=[&](size_t n){ n=ru8(n); bf16* p=bb+bo; bo+=n; return p; };
        bf16* sEh = B2((size_t)40*CF); bf16* sEl = B2((size_t)40*CF);
        bf16 *Ph[3], *Pl[3];
        for (int t=0;t<3;t++){ Ph[t]=B2((size_t)256*CF); Pl[t]=B2((size_t)256*CF); }

        auto eval_sdf = [&](const float* ptsrc, int np, float* outbuf, int per_ray, int stride){
            for (int o3=0; o3<np; o3+=CF){
                int n = (np-o3 < CF) ? (np-o3) : CF;
                dim3 gb1((n+255)/256), gb256((n*256+255)/256), b(256);
                k_embed<<<gb1,b,0,stream>>>(ptsrc+(size_t)o3*3, sE, sEh, sEl, n);
                GArgs g{};
                auto fwd = [&](const bf16* Ah,const bf16* Al,int lda,int wl,
                               bf16* Ch,bf16* Cl,float* Cf,int ldcf,int N,int K){
                    g = GArgs{}; g.Ah=Ah; g.Al=Al; g.lda=lda;
                    g.Bh=wp.tH[wl]; g.Bl=wp.tL[wl]; g.ldb=wp.ldt[wl]; g.bias=sb[wl];
                    g.Ch=Ch; g.Cl=Cl; g.ldc=256; g.Cf=Cf; g.ldcf=ldcf;
                    g.M=n; g.N=N; g.K=K;
                    mg(stream, 1, g);
                };
                fwd(sEh,sEl,40, 0, Ph[0],Pl[0], nullptr,0, 256,39);
                fwd(Ph[0],Pl[0],256, 1, Ph[1],Pl[1], nullptr,0, 256,256);
                fwd(Ph[1],Pl[1],256, 2, Ph[2],Pl[2], nullptr,0, 256,256);
                fwd(Ph[2],Pl[2],256, 3, nullptr,nullptr, sH3,217, 217,256);
                k_concat<<<gb256,b,0,stream>>>(sH3, sE, Ph[0], Pl[0], n);
                fwd(Ph[0],Pl[0],256, 4, Ph[1],Pl[1], nullptr,0, 256,256);
                fwd(Ph[1],Pl[1],256, 5, Ph[2],Pl[2], nullptr,0, 256,256);
                fwd(Ph[2],Pl[2],256, 6, Ph[0],Pl[0], nullptr,0, 256,256);
                fwd(Ph[0],Pl[0],256, 7, nullptr,nullptr, sH7,256, 256,256);
                k_sdf_tail<<<(n*64+255)/256,256,0,stream>>>(sH7, sw[8], sb[8], outbuf, n, o3, per_ray, stride);
            }
        };

        eval_sdf(pts, 65536, sA, 64, 128);
        for (int it=0; it<4; it++){
            int S = 64 + 16*it;
            float* zsrc = (it&1)? zB : zA;  float* ssrc = (it&1)? sB : sA;
            float* zdst = (it&1)? zA : zB;  float* sdst = (it&1)? sA : sB;
            float inv_s = 64.f * (float)(1<<it);
            k_upsample<<<NR/64,64,0,stream>>>(rays_o, rays_d, zsrc, ssrc, S, inv_s, nzb);
            k_pts<<<(NR*16+255)/256,256,0,stream>>>(nzb, 16, 16, rays_o, rays_d, pts, NR*16);
            eval_sdf(pts, NR*16, nsb, 16, 16);
            k_merge<<<NR/64,64,0,stream>>>(zsrc, ssrc, nzb, nsb, S, zdst, sdst);
        }
    }
    // final z in zA

    // ---- final phase ----
    {
        size_t o2 = 0;
        auto F2=[&](size_t n){ float* p=scratch+o2; o2+=n; return p; };
        float* ptsl  = F2((size_t)3*CHF);
        float* fE    = F2((size_t)39*CHF);
        float* fH3   = F2((size_t)217*CHF);
        float* bufF  = F2((size_t)256*CHF);
        float* din0f = F2((size_t)39*CHF);
        float* detl  = F2((size_t)39*CHF);
        bf16* bb = (bf16*)(scratch+o2);
        size_t bo=0;
        auto B2=[&](size_t n){ n=ru8(n); bf16* p=bb+bo; bo+=n; return p; };
        bf16* fEh = B2((size_t)40*CHF); bf16* fEl = B2((size_t)40*CHF);
        bf16 *Ph[3], *Pl[3];
        for (int t=0;t<3;t++){ Ph[t]=B2((size_t)256*CHF); Pl[t]=B2((size_t)256*CHF); }
        bf16* cinH = B2((size_t)272*CHF); bf16* cinL = B2((size_t)272*CHF);
        bf16* fac[8];
        for (int l=0;l<8;l++) fac[l] = B2((size_t)((l==3)?217:256)*CHF);

        for (int offp=0; offp<NR*128; offp+=CHF){
            int n = (NR*128-offp < CHF) ? (NR*128-offp) : CHF;
            dim3 gb1((n+255)/256), gb256((n*256+255)/256), b(256);
            k_pts_mid<<<gb1,b,0,stream>>>(zA, rays_o, rays_d, offp, n, ptsl);
            k_embed<<<gb1,b,0,stream>>>(ptsl, fE, fEh, fEl, n);

            GArgs g{};
            auto fwd = [&](const bf16* Ah,const bf16* Al,int lda,int wl,
                           bf16* Ch,bf16* Cl,bf16* Cfac,int ldcfac,
                           float* Cf,int ldcf,int N,int K){
                g = GArgs{}; g.Ah=Ah; g.Al=Al; g.lda=lda;
                g.Bh=wp.tH[wl]; g.Bl=wp.tL[wl]; g.ldb=wp.ldt[wl]; g.bias=sb[wl];
                g.Ch=Ch; g.Cl=Cl; g.ldc=256; g.Cfac=Cfac; g.ldcfac=ldcfac;
                g.Cf=Cf; g.ldcf=ldcf; g.M=n; g.N=N; g.K=K;
                mg(stream, 1, g);
            };
            fwd(fEh,fEl,40, 0, Ph[0],Pl[0], fac[0],256, nullptr,0, 256,39);
            fwd(Ph[0],Pl[0],256, 1, Ph[1],Pl[1], fac[1],256, nullptr,0, 256,256);
            fwd(Ph[1],Pl[1],256, 2, Ph[2],Pl[2], fac[2],256, nullptr,0, 256,256);
            fwd(Ph[2],Pl[2],256, 3, nullptr,nullptr, fac[3],217, fH3,217, 217,256);
            k_concat<<<gb256,b,0,stream>>>(fH3, fE, Ph[0], Pl[0], n);
            fwd(Ph[0],Pl[0],256, 4, Ph[1],Pl[1], fac[4],256, nullptr,0, 256,256);
            fwd(Ph[1],Pl[1],256, 5, Ph[2],Pl[2], fac[5],256, nullptr,0, 256,256);
            fwd(Ph[2],Pl[2],256, 6, Ph[0],Pl[0], fac[6],256, nullptr,0, 256,256);
            fwd(Ph[0],Pl[0],256, 7, Ph[1],Pl[1], fac[7],256, nullptr,0, 256,256);
            // L8: sdf + feat -> cin planes
            g = GArgs{}; g.Ah=Ph[1]; g.Al=Pl[1]; g.lda=256;
            g.Bh=wp.tH[8]; g.Bl=wp.tL[8]; g.ldb=wp.ldt[8]; g.bias=sb[8];
            g.Ch=cinH; g.Cl=cinL; g.ldc=272; g.sdfo=sdfF+offp;
            g.M=n; g.N=257; g.K=256;
            mg(stream, 5, g);
            // backward
            k_bwd_init<<<gb256,b,0,stream>>>(sw[8], fac[7], Ph[0], Pl[0], n);
            auto bwd = [&](const bf16* Ah,const bf16* Al,int lda,int wl,const bf16* fc,int ldfc,
                           bf16* Ch,bf16* Cl,int N,int K){
                g = GArgs{}; g.Ah=Ah; g.Al=Al; g.lda=lda;
                g.Bh=wp.nH[wl]; g.ldb=wp.ldn[wl];
                g.fac=fc; g.ldfac=ldfc;
                g.Ch=Ch; g.Cl=Cl; g.ldc=256;
                g.M=n; g.N=N; g.K=K;
                mg(stream, 3, g);
            };
            bwd(Ph[0],Pl[0],256, 7, fac[6],256, Ph[1],Pl[1], 256,256); // dZ6
            bwd(Ph[1],Pl[1],256, 6, fac[5],256, Ph[2],Pl[2], 256,256); // dZ5
            bwd(Ph[2],Pl[2],256, 5, fac[4],256, Ph[0],Pl[0], 256,256); // dZ4
            // din4 (linear)
            g = GArgs{}; g.Ah=Ph[0]; g.Al=Pl[0]; g.lda=256;
            g.Bh=wp.nH[4]; g.ldb=wp.ldn[4];
            g.Cf=bufF; g.ldcf=256; g.M=n; g.N=256; g.K=256;
            mg(stream, 0, g);
            k_split4<<<gb256,b,0,stream>>>(bufF, fac[3], Ph[1], Pl[1], detl, n);
            bwd(Ph[1],Pl[1],256, 3, fac[2],256, Ph[2],Pl[2], 256,217); // dZ2
            bwd(Ph[2],Pl[2],256, 2, fac[1],256, Ph[0],Pl[0], 256,256); // dZ1
            bwd(Ph[0],Pl[0],256, 1, fac[0],256, Ph[1],Pl[1], 256,256); // dZ0
            // din0 (linear, N=39)
            g = GArgs{}; g.Ah=Ph[1]; g.Al=Pl[1]; g.lda=256;
            g.Bh=wp.nH[0]; g.ldb=wp.ldn[0];
            g.Cf=din0f; g.ldcf=39; g.M=n; g.N=39; g.K=256;
            mg(stream, 0, g);
            k_emb_bwd<<<gb1,b,0,stream>>>(ptsl, din0f, detl, rays_d, offp, n, cinH, cinL, tcos);
            // color MLP
            g = GArgs{}; g.Ah=cinH; g.Al=cinL; g.lda=272;
            g.Bh=wp.tH[9]; g.Bl=wp.tL[9]; g.ldb=wp.ldt[9]; g.bias=cb0;
            g.Ch=Ph[0]; g.Cl=Pl[0]; g.ldc=256; g.M=n; g.N=256; g.K=265;
            mg(stream, 2, g);
            g = GArgs{}; g.Ah=Ph[0]; g.Al=Pl[0]; g.lda=256;
            g.Bh=wp.tH[10]; g.Bl=wp.tL[10]; g.ldb=wp.ldt[10]; g.bias=cb1;
            g.Cf=bufF; g.ldcf=256; g.M=n; g.N=256; g.K=256;
            mg(stream, 2, g);
            k_rgb<<<(n*64+255)/256,256,0,stream>>>(bufF, cw2, cb2, rgbs+(size_t)offp*3, n);
        }
    }
    k_composite<<<NR/64,64,0,stream>>>(zA, sdfF, tcos, rgbs, varp, out);
}

// Round 3
// 5966.504 us; speedup vs baseline: 3.3953x; 1.5382x over previous
//
#include <hip/hip_runtime.h>
#include <math.h>

#define NR 1024
#define AS 264    // fwd/bwd activation LDS stride (bf16)
#define AS2 296   // color activation LDS stride (bf16)
#define BS 40     // weight tile LDS stride (bf16)
#define IS2 0.70710678118654752f

typedef __bf16 bf16;
typedef bf16 bf16x8 __attribute__((ext_vector_type(8)));
typedef float floatx4 __attribute__((ext_vector_type(4)));

__device__ __forceinline__ float sp100f(float z){
    float x = 100.f*z;
    return (fmaxf(x,0.f) + log1pf(expf(-fabsf(x)))) * 0.01f;
}
__device__ __forceinline__ float sigm(float x){ return 1.f/(1.f+expf(-x)); }

// ---------- weight tile staging (reg-staged, guarded) ----------
struct StReg { bf16x8 v[4]; };

__device__ __forceinline__ StReg stage_load(const bf16* __restrict__ P, int ld, int NV, int KV, int k0){
    StReg r; int n = threadIdx.x;
    const bf16* src = P + (size_t)n*ld + k0;
    bool nv = n < NV;
    int rem = KV - k0;
    if (nv && rem >= 32){
        r.v[0]=*(const bf16x8*)src;      r.v[1]=*(const bf16x8*)(src+8);
        r.v[2]=*(const bf16x8*)(src+16); r.v[3]=*(const bf16x8*)(src+24);
    } else {
        #pragma unroll
        for (int q=0;q<4;q++){
            bf16x8 v = {};
            if (nv){
                #pragma unroll
                for (int j=0;j<8;j++) if (q*8+j < rem) v[j] = src[q*8+j];
            }
            r.v[q]=v;
        }
    }
    return r;
}
__device__ __forceinline__ void stage_write(const StReg& r, bf16* dst){
    bf16* d = dst + threadIdx.x*BS;
    *(bf16x8*)d      = r.v[0]; *(bf16x8*)(d+8)  = r.v[1];
    *(bf16x8*)(d+16) = r.v[2]; *(bf16x8*)(d+24) = r.v[3];
}

// ---------- in-kernel GEMM step: acc = A_lds @ W^T (W staged per K-tile) ----------
// PASSES==3: AhBh + AlBh + AhBl ; PASSES==2: AhBh + AlBh
template<int PASSES, int ASP>
__device__ __forceinline__ void mlp_gemm(
    const bf16* __restrict__ Wh, const bf16* __restrict__ Wl, int ld, int NV, int KV,
    const bf16* Ahs, const bf16* Als, bf16* Bhs, bf16* Bls,
    floatx4 (&acc)[2][8], int wr, int cb, int lr, int lq)
{
    #pragma unroll
    for (int i=0;i<2;i++)
        #pragma unroll
        for (int j=0;j<8;j++) acc[i][j] = floatx4{0.f,0.f,0.f,0.f};
    const int nk = (KV+31)>>5;
    {
        StReg rh = stage_load(Wh, ld, NV, KV, 0); stage_write(rh, Bhs);
        if (PASSES==3){ StReg rl = stage_load(Wl, ld, NV, KV, 0); stage_write(rl, Bls); }
    }
    for (int kt=0; kt<nk; kt++){
        __syncthreads();
        StReg ph, pl; bool pf = (kt+1)<nk;
        if (pf){
            ph = stage_load(Wh, ld, NV, KV, (kt+1)*32);
            if (PASSES==3) pl = stage_load(Wl, ld, NV, KV, (kt+1)*32);
        }
        const bf16* bh = Bhs + (kt&1)*256*BS;
        const int ab = (wr*32+lr)*ASP + kt*32 + lq*8;
        bf16x8 a0h = *(const bf16x8*)&Ahs[ab];
        bf16x8 a1h = *(const bf16x8*)&Ahs[ab+16*ASP];
        bf16x8 a0l = *(const bf16x8*)&Als[ab];
        bf16x8 a1l = *(const bf16x8*)&Als[ab+16*ASP];
        #pragma unroll
        for (int j=0;j<8;j++){
            const int bo = (cb+j*16+lr)*BS + lq*8;
            bf16x8 vh = *(const bf16x8*)&bh[bo];
            acc[0][j] = __builtin_amdgcn_mfma_f32_16x16x32_bf16(a0h, vh, acc[0][j],0,0,0);
            acc[1][j] = __builtin_amdgcn_mfma_f32_16x16x32_bf16(a1h, vh, acc[1][j],0,0,0);
            acc[0][j] = __builtin_amdgcn_mfma_f32_16x16x32_bf16(a0l, vh, acc[0][j],0,0,0);
            acc[1][j] = __builtin_amdgcn_mfma_f32_16x16x32_bf16(a1l, vh, acc[1][j],0,0,0);
            if (PASSES==3){
                const bf16* bl = Bls + (kt&1)*256*BS;
                bf16x8 vl = *(const bf16x8*)&bl[bo];
                acc[0][j] = __builtin_amdgcn_mfma_f32_16x16x32_bf16(a0h, vl, acc[0][j],0,0,0);
                acc[1][j] = __builtin_amdgcn_mfma_f32_16x16x32_bf16(a1h, vl, acc[1][j],0,0,0);
            }
        }
        if (pf){
            stage_write(ph, Bhs + ((kt+1)&1)*256*BS);
            if (PASSES==3) stage_write(pl, Bls + ((kt+1)&1)*256*BS);
        }
    }
    __syncthreads();
}

// ---------- fused forward SDF MLP ----------
struct FwdArgs {
    const float* pts;
    const bf16 *wh[9], *wl[9]; int wld[9];
    const float* bias[9];
    const float* w8col;           // sw[8], stride 257 (col 0)
    float* sdfo; int soff, sper, sstr;
    bf16 *cinH, *cinL;            // MODE 1
    bf16* fac[8]; int facld[8];   // MODE 1
};

template<int MODE>  // 0 = sampling (sdf only), 1 = final (fac + cin feat + sdf)
__global__ __launch_bounds__(256,1) void k_fwd(FwdArgs a)
{
    __shared__ bf16 Ahs[64*AS], Als[64*AS];
    __shared__ bf16 Bhs[2*256*BS], Bls[2*256*BS];
    __shared__ float Ef[64][40];
    __shared__ float W8s[256];
    const int tid=threadIdx.x, wid=tid>>6, lane=tid&63, lr=lane&15, lq=lane>>4;
    const int wr=wid>>1, cb=(wid&1)*128;
    const int bm = blockIdx.x*64;

    W8s[tid] = a.w8col[(size_t)tid*257];
    if (tid<64){
        const float* pp = a.pts + (size_t)(bm+tid)*3;
        float p0=pp[0],p1=pp[1],p2=pp[2];
        float vals[39];
        vals[0]=p0; vals[1]=p1; vals[2]=p2;
        float fq=1.f;
        #pragma unroll
        for (int q=0;q<6;q++){
            vals[3+6*q+0]=sinf(fq*p0); vals[3+6*q+1]=sinf(fq*p1); vals[3+6*q+2]=sinf(fq*p2);
            vals[3+6*q+3]=cosf(fq*p0); vals[3+6*q+4]=cosf(fq*p1); vals[3+6*q+5]=cosf(fq*p2);
            fq *= 2.f;
        }
        bf16* ah=&Ahs[tid*AS]; bf16* al=&Als[tid*AS];
        #pragma unroll
        for (int j=0;j<39;j++){
            float v=vals[j]; Ef[tid][j]=v;
            bf16 h=(bf16)v; ah[j]=h; al[j]=(bf16)(v-(float)h);
        }
        #pragma unroll
        for (int j=39;j<64;j++){ ah[j]=(bf16)0.f; al[j]=(bf16)0.f; }
    }

    floatx4 acc[2][8];
    auto wb_act = [&](const float* bias, bf16* facp, int fld, bool l3){
        #pragma unroll
        for (int i=0;i<2;i++){
            int rbase = wr*32+i*16+lq*4;
            #pragma unroll
            for (int j=0;j<8;j++){
                int col = cb+j*16+lr;
                bool ok = (!l3) || (col<217);
                float bv = ok ? bias[col] : 0.f;
                #pragma unroll
                for (int r=0;r<4;r++){
                    if (!ok) continue;
                    int row = rbase+r;
                    float v = acc[i][j][r]+bv;
                    if (MODE==1) facp[(size_t)(bm+row)*fld+col] = (bf16)sigm(100.f*v);
                    float act = sp100f(v); if (l3) act *= IS2;
                    bf16 h=(bf16)act;
                    Ahs[row*AS+col]=h; Als[row*AS+col]=(bf16)(act-(float)h);
                }
            }
        }
    };

    // L0 (K=39)
    mlp_gemm<3,AS>(a.wh[0],a.wl[0],a.wld[0],256,39, Ahs,Als,Bhs,Bls, acc, wr,cb,lr,lq);
    wb_act(a.bias[0], MODE? a.fac[0]:(bf16*)nullptr, 256, false);
    // L1, L2
    mlp_gemm<3,AS>(a.wh[1],a.wl[1],a.wld[1],256,256, Ahs,Als,Bhs,Bls, acc, wr,cb,lr,lq);
    wb_act(a.bias[1], MODE? a.fac[1]:(bf16*)nullptr, 256, false);
    mlp_gemm<3,AS>(a.wh[2],a.wl[2],a.wld[2],256,256, Ahs,Als,Bhs,Bls, acc, wr,cb,lr,lq);
    wb_act(a.bias[2], MODE? a.fac[2]:(bf16*)nullptr, 256, false);
    // L3 (N=217, scaled by 1/sqrt2) + e-concat
    mlp_gemm<3,AS>(a.wh[3],a.wl[3],a.wld[3],217,256, Ahs,Als,Bhs,Bls, acc, wr,cb,lr,lq);
    wb_act(a.bias[3], MODE? a.fac[3]:(bf16*)nullptr, 217, true);
    if (tid<64){
        bf16* ah=&Ahs[tid*AS]; bf16* al=&Als[tid*AS];
        #pragma unroll
        for (int c=217;c<256;c++){
            float v = Ef[tid][c-217]*IS2;
            bf16 h=(bf16)v; ah[c]=h; al[c]=(bf16)(v-(float)h);
        }
    }
    // L4..L7
    mlp_gemm<3,AS>(a.wh[4],a.wl[4],a.wld[4],256,256, Ahs,Als,Bhs,Bls, acc, wr,cb,lr,lq);
    wb_act(a.bias[4], MODE? a.fac[4]:(bf16*)nullptr, 256, false);
    mlp_gemm<3,AS>(a.wh[5],a.wl[5],a.wld[5],256,256, Ahs,Als,Bhs,Bls, acc, wr,cb,lr,lq);
    wb_act(a.bias[5], MODE? a.fac[5]:(bf16*)nullptr, 256, false);
    mlp_gemm<3,AS>(a.wh[6],a.wl[6],a.wld[6],256,256, Ahs,Als,Bhs,Bls, acc, wr,cb,lr,lq);
    wb_act(a.bias[6], MODE? a.fac[6]:(bf16*)nullptr, 256, false);
    mlp_gemm<3,AS>(a.wh[7],a.wl[7],a.wld[7],256,256, Ahs,Als,Bhs,Bls, acc, wr,cb,lr,lq);
    wb_act(a.bias[7], MODE? a.fac[7]:(bf16*)nullptr, 256, false);

    if (MODE==1){
        // L8 feat: cols 1..256 of W8 -> cin cols 9..264
        mlp_gemm<3,AS>(a.wh[8]+a.wld[8], a.wl[8]+a.wld[8], a.wld[8], 256,256,
                       Ahs,Als,Bhs,Bls, acc, wr,cb,lr,lq);
        #pragma unroll
        for (int i=0;i<2;i++){
            int rbase = wr*32+i*16+lq*4;
            #pragma unroll
            for (int j=0;j<8;j++){
                int col = cb+j*16+lr;
                float bv = a.bias[8][1+col];
                #pragma unroll
                for (int r=0;r<4;r++){
                    int row = rbase+r;
                    float v = acc[i][j][r]+bv;
                    bf16 h=(bf16)v;
                    a.cinH[(size_t)(bm+row)*272 + 9+col]=h;
                    a.cinL[(size_t)(bm+row)*272 + 9+col]=(bf16)(v-(float)h);
                }
            }
        }
    }
    __syncthreads();
    // sdf = h7 . W8[:,0] + b8[0]
    {
        int row = wid*16+lr;
        const bf16* ah=&Ahs[row*AS+lq*64]; const bf16* al=&Als[row*AS+lq*64];
        float s=0.f;
        #pragma unroll
        for (int c=0;c<8;c++){
            bf16x8 vh=*(const bf16x8*)(ah+c*8), vl=*(const bf16x8*)(al+c*8);
            #pragma unroll
            for (int j=0;j<8;j++) s += ((float)vh[j]+(float)vl[j]) * W8s[lq*64+c*8+j];
        }
        s += __shfl_xor(s,16,64); s += __shfl_xor(s,32,64);
        if (lq==0){
            int p = a.soff + bm + row;
            a.sdfo[(p/a.sper)*a.sstr + (p%a.sper)] = s + a.bias[8][0];
        }
    }
}

// ---------- fused backward (sdf grad wrt pts) + emb_bwd ----------
struct BwdArgs {
    const bf16* nh[8]; int ldn[8];
    const bf16* fac[8]; int facld[8];
    const float* w8col;
    const float* pts; const float* raysd;
    bf16 *cinH, *cinL;
    float* tcos; int offp;
};

__global__ __launch_bounds__(256,1) void k_bwd(BwdArgs a)
{
    __shared__ bf16 Ahs[64*AS], Als[64*AS];
    __shared__ bf16 Bhs[2*256*BS];
    __shared__ float detl[64][40];
    __shared__ float dn0[64][40];
    __shared__ float W8s[256];
    const int tid=threadIdx.x, wid=tid>>6, lane=tid&63, lr=lane&15, lq=lane>>4;
    const int wr=wid>>1, cb=(wid&1)*128;
    const int bm = blockIdx.x*64;

    W8s[tid] = a.w8col[(size_t)tid*257];
    __syncthreads();
    // dZ7 = W8[:,0] * fac7
    for (int c=0;c<64;c++){
        float v = W8s[tid] * (float)a.fac[7][(size_t)(bm+c)*256 + tid];
        bf16 h=(bf16)v;
        Ahs[c*AS+tid]=h; Als[c*AS+tid]=(bf16)(v-(float)h);
    }

    floatx4 acc[2][8];
    auto wb_fac = [&](const bf16* fc, int fld){
        #pragma unroll
        for (int i=0;i<2;i++){
            int rbase = wr*32+i*16+lq*4;
            #pragma unroll
            for (int j=0;j<8;j++){
                int col = cb+j*16+lr;
                #pragma unroll
                for (int r=0;r<4;r++){
                    int row = rbase+r;
                    float v = acc[i][j][r] * (float)fc[(size_t)(bm+row)*fld+col];
                    bf16 h=(bf16)v;
                    Ahs[row*AS+col]=h; Als[row*AS+col]=(bf16)(v-(float)h);
                }
            }
        }
    };

    mlp_gemm<2,AS>(a.nh[7],nullptr,a.ldn[7],256,256, Ahs,Als,Bhs,nullptr, acc, wr,cb,lr,lq);
    wb_fac(a.fac[6],256);
    mlp_gemm<2,AS>(a.nh[6],nullptr,a.ldn[6],256,256, Ahs,Als,Bhs,nullptr, acc, wr,cb,lr,lq);
    wb_fac(a.fac[5],256);
    mlp_gemm<2,AS>(a.nh[5],nullptr,a.ldn[5],256,256, Ahs,Als,Bhs,nullptr, acc, wr,cb,lr,lq);
    wb_fac(a.fac[4],256);
    // din4 -> split
    mlp_gemm<2,AS>(a.nh[4],nullptr,a.ldn[4],256,256, Ahs,Als,Bhs,nullptr, acc, wr,cb,lr,lq);
    #pragma unroll
    for (int i=0;i<2;i++){
        int rbase = wr*32+i*16+lq*4;
        #pragma unroll
        for (int j=0;j<8;j++){
            int col = cb+j*16+lr;
            #pragma unroll
            for (int r=0;r<4;r++){
                int row = rbase+r;
                float v = acc[i][j][r]*IS2;
                if (col<217){
                    v *= (float)a.fac[3][(size_t)(bm+row)*217+col];
                    bf16 h=(bf16)v;
                    Ahs[row*AS+col]=h; Als[row*AS+col]=(bf16)(v-(float)h);
                } else {
                    detl[row][col-217]=v;
                    Ahs[row*AS+col]=(bf16)0.f; Als[row*AS+col]=(bf16)0.f;
                }
            }
        }
    }
    mlp_gemm<2,AS>(a.nh[3],nullptr,a.ldn[3],256,217, Ahs,Als,Bhs,nullptr, acc, wr,cb,lr,lq);
    wb_fac(a.fac[2],256);
    mlp_gemm<2,AS>(a.nh[2],nullptr,a.ldn[2],256,256, Ahs,Als,Bhs,nullptr, acc, wr,cb,lr,lq);
    wb_fac(a.fac[1],256);
    mlp_gemm<2,AS>(a.nh[1],nullptr,a.ldn[1],256,256, Ahs,Als,Bhs,nullptr, acc, wr,cb,lr,lq);
    wb_fac(a.fac[0],256);
    // din0 (N=39)
    mlp_gemm<2,AS>(a.nh[0],nullptr,a.ldn[0],39,256, Ahs,Als,Bhs,nullptr, acc, wr,cb,lr,lq);
    #pragma unroll
    for (int i=0;i<2;i++){
        int rbase = wr*32+i*16+lq*4;
        #pragma unroll
        for (int j=0;j<8;j++){
            int col = cb+j*16+lr;
            if (col<39){
                #pragma unroll
                for (int r=0;r<4;r++) dn0[rbase+r][col] = acc[i][j][r];
            }
        }
    }
    __syncthreads();
    // emb backward + cin cols 0..8 (+zero 265..271)
    if (tid<64){
        int p = a.offp + bm + tid;
        int rI = p>>7;
        const float* pp = a.pts + (size_t)(bm+tid)*3;
        float px=pp[0],py=pp[1],pz=pp[2];
        float g0=dn0[tid][0]+detl[tid][0];
        float g1=dn0[tid][1]+detl[tid][1];
        float g2=dn0[tid][2]+detl[tid][2];
        float fq=1.f;
        #pragma unroll
        for (int q=0;q<6;q++){
            int base=3+6*q;
            float ds0=dn0[tid][base+0]+detl[tid][base+0];
            float ds1=dn0[tid][base+1]+detl[tid][base+1];
            float ds2=dn0[tid][base+2]+detl[tid][base+2];
            float dc0=dn0[tid][base+3]+detl[tid][base+3];
            float dc1=dn0[tid][base+4]+detl[tid][base+4];
            float dc2=dn0[tid][base+5]+detl[tid][base+5];
            g0 += fq*(cosf(fq*px)*ds0 - sinf(fq*px)*dc0);
            g1 += fq*(cosf(fq*py)*ds1 - sinf(fq*py)*dc1);
            g2 += fq*(cosf(fq*pz)*ds2 - sinf(fq*pz)*dc2);
            fq *= 2.f;
        }
        float dx=a.raysd[3*rI],dy=a.raysd[3*rI+1],dz=a.raysd[3*rI+2];
        a.tcos[p] = dx*g0+dy*g1+dz*g2;
        float nm = fmaxf(sqrtf(g0*g0+g1*g1+g2*g2), 1e-6f);
        float vals[9] = {px,py,pz,dx,dy,dz,g0/nm,g1/nm,g2/nm};
        bf16* ch = a.cinH + (size_t)(bm+tid)*272;
        bf16* cl = a.cinL + (size_t)(bm+tid)*272;
        #pragma unroll
        for (int c=0;c<9;c++){
            float v=vals[c]; bf16 h=(bf16)v;
            ch[c]=h; cl[c]=(bf16)(v-(float)h);
        }
        #pragma unroll
        for (int c=265;c<272;c++){ ch[c]=(bf16)0.f; cl[c]=(bf16)0.f; }
    }
}

// ---------- fused color MLP ----------
struct ColArgs {
    const bf16 *cinH, *cinL;
    const bf16 *w0h,*w0l; int ld0; const float* b0;
    const bf16 *w1h,*w1l; const float* b1;
    const float* w2; const float* b2;
    float* rgb;
};

__global__ __launch_bounds__(256,1) void k_col(ColArgs a)
{
    __shared__ bf16 Ahs[64*AS2], Als[64*AS2];
    __shared__ bf16 Bhs[2*256*BS], Bls[2*256*BS];
    __shared__ float W2s[256*3];
    const int tid=threadIdx.x, wid=tid>>6, lane=tid&63, lr=lane&15, lq=lane>>4;
    const int wr=wid>>1, cb=(wid&1)*128;
    const int bm = blockIdx.x*64;

    W2s[tid*3]=a.w2[tid*3]; W2s[tid*3+1]=a.w2[tid*3+1]; W2s[tid*3+2]=a.w2[tid*3+2];
    // stage cin (hi/lo) into LDS
    {
        int row = tid&63, part = tid>>6;
        const bf16* src = (part&2)? a.cinL : a.cinH;
        bf16* dst = (part&2)? Als : Ahs;
        int c0 = (part&1)*136;
        const bf16* s = src + (size_t)(bm+row)*272 + c0;
        bf16* d = dst + row*AS2 + c0;
        #pragma unroll
        for (int v=0;v<17;v++) *(bf16x8*)(d+v*8) = *(const bf16x8*)(s+v*8);
        if (part&1){
            bf16x8 z = {};
            bf16* zd = dst + row*AS2 + 272;
            #pragma unroll
            for (int v=0;v<3;v++) *(bf16x8*)(zd+v*8) = z;
        }
    }

    floatx4 acc[2][8];
    auto wb_relu = [&](const float* bias){
        #pragma unroll
        for (int i=0;i<2;i++){
            int rbase = wr*32+i*16+lq*4;
            #pragma unroll
            for (int j=0;j<8;j++){
                int col = cb+j*16+lr;
                float bv = bias[col];
                #pragma unroll
                for (int r=0;r<4;r++){
                    int row = rbase+r;
                    float v = fmaxf(acc[i][j][r]+bv, 0.f);
                    bf16 h=(bf16)v;
                    Ahs[row*AS2+col]=h; Als[row*AS2+col]=(bf16)(v-(float)h);
                }
            }
        }
    };
    mlp_gemm<3,AS2>(a.w0h,a.w0l,a.ld0,256,272, Ahs,Als,Bhs,Bls, acc, wr,cb,lr,lq);
    wb_relu(a.b0);
    mlp_gemm<3,AS2>(a.w1h,a.w1l,256,256,256, Ahs,Als,Bhs,Bls, acc, wr,cb,lr,lq);
    wb_relu(a.b1);
    __syncthreads();
    // rgb = sigmoid(h @ cw2 + cb2)
    {
        int row = wid*16+lr;
        const bf16* ah=&Ahs[row*AS2+lq*64]; const bf16* al=&Als[row*AS2+lq*64];
        float s0=0.f,s1=0.f,s2=0.f;
        #pragma unroll
        for (int c=0;c<8;c++){
            bf16x8 vh=*(const bf16x8*)(ah+c*8), vl=*(const bf16x8*)(al+c*8);
            #pragma unroll
            for (int j=0;j<8;j++){
                float f = (float)vh[j]+(float)vl[j];
                int k = lq*64+c*8+j;
                s0 += f*W2s[k*3]; s1 += f*W2s[k*3+1]; s2 += f*W2s[k*3+2];
            }
        }
        s0 += __shfl_xor(s0,16,64); s0 += __shfl_xor(s0,32,64);
        s1 += __shfl_xor(s1,16,64); s1 += __shfl_xor(s1,32,64);
        s2 += __shfl_xor(s2,16,64); s2 += __shfl_xor(s2,32,64);
        if (lq==0){
            float* o = a.rgb + (size_t)(bm+row)*3;
            o[0]=sigm(s0+a.b2[0]); o[1]=sigm(s1+a.b2[1]); o[2]=sigm(s2+a.b2[2]);
        }
    }
}

// ---------- weight conversion ----------
struct ConvDesc { const float* src; bf16 *th, *tl, *nh; int K, N, ldt, ldn; };
struct ConvArgs { ConvDesc d[11]; };
__global__ void k_conv(ConvArgs a){
    ConvDesc cd = a.d[blockIdx.y];
    int idx = blockIdx.x*256+threadIdx.x;
    if (idx >= cd.K*cd.N) return;
    int k = idx / cd.N, n = idx - k*cd.N;
    float v = cd.src[idx];
    bf16 h = (bf16)v;
    cd.th[(size_t)n*cd.ldt + k] = h;
    cd.tl[(size_t)n*cd.ldt + k] = (bf16)(v - (float)h);
    if (cd.nh) cd.nh[(size_t)k*cd.ldn + n] = h;
}

// ---------- small kernels ----------
__global__ void k_ray_setup(const float* __restrict__ o, const float* __restrict__ d,
                            float* __restrict__ z)
{
    int r = blockIdx.x; int i = threadIdx.x;
    float ox=o[3*r],oy=o[3*r+1],oz=o[3*r+2];
    float dx=d[3*r],dy=d[3*r+1],dz=d[3*r+2];
    float a = dx*dx+dy*dy+dz*dz;
    float b = 2.f*(ox*dx+oy*dy+oz*dz);
    float mid = -b/(2.f*a);
    float nearv = fmaxf(mid-1.f, 0.05f);
    float farv = mid+1.f;
    z[r*128+i] = nearv + (farv-nearv)*((float)i/63.f);
}

__global__ void k_pts(const float* __restrict__ zbuf, int per_ray, int stride,
                      const float* __restrict__ o, const float* __restrict__ d,
                      float* __restrict__ pts, int np)
{
    int i = blockIdx.x*256+threadIdx.x; if (i>=np) return;
    int r = i/per_ray, k = i%per_ray;
    float z = zbuf[r*stride+k];
    pts[3*i+0] = o[3*r+0]+d[3*r+0]*z;
    pts[3*i+1] = o[3*r+1]+d[3*r+1]*z;
    pts[3*i+2] = o[3*r+2]+d[3*r+2]*z;
}

__global__ void k_pts_mid(const float* __restrict__ z, const float* __restrict__ o,
                          const float* __restrict__ d, int off, int n,
                          float* __restrict__ pts)
{
    int i = blockIdx.x*256+threadIdx.x; if (i>=n) return;
    int p = off+i; int r = p>>7; int sI = p&127;
    float zv = z[r*128+sI];
    float dist = (sI<127) ? z[r*128+sI+1]-zv : 0.03125f;
    float mid = zv + 0.5f*dist;
    pts[3*i+0]=o[3*r+0]+d[3*r+0]*mid;
    pts[3*i+1]=o[3*r+1]+d[3*r+1]*mid;
    pts[3*i+2]=o[3*r+2]+d[3*r+2]*mid;
}

__global__ void k_upsample(const float* __restrict__ o, const float* __restrict__ d,
                           const float* __restrict__ z, const float* __restrict__ sdf,
                           int S, float inv_s, float* __restrict__ new_z)
{
    int r = blockIdx.x*64+threadIdx.x; if (r>=NR) return;
    const float* zr = z + r*128;
    const float* sr = sdf + r*128;
    float ox=o[3*r],oy=o[3*r+1],oz=o[3*r+2];
    float dx=d[3*r],dy=d[3*r+1],dz=d[3*r+2];
    float w[128];
    float cdf[129];
    float wsum=0.f, T=1.f, raw_prev=0.f;
    float z0 = zr[0];
    float px=ox+dx*z0, py=oy+dy*z0, pz=oz+dz*z0;
    float r0 = sqrtf(px*px+py*py+pz*pz);
    for (int i=0;i<S-1;i++){
        float z1 = zr[i+1];
        float qx=ox+dx*z1, qy=oy+dy*z1, qz=oz+dz*z1;
        float r1 = sqrtf(qx*qx+qy*qy+qz*qz);
        bool inside = (r0<1.f)||(r1<1.f);
        float s0=sr[i], s1=sr[i+1];
        float zc = zr[i];
        float mid_sdf = 0.5f*(s0+s1);
        float raw = (s1-s0)/(z1-zc+1e-5f);
        float cv = fminf(raw, (i==0)?0.f:raw_prev);
        raw_prev = raw;
        cv = fminf(fmaxf(cv,-1000.f),0.f);
        if (!inside) cv = 0.f;
        float dist = z1-zc;
        float pe = mid_sdf - cv*dist*0.5f;
        float ne = mid_sdf + cv*dist*0.5f;
        float pc = sigm(pe*inv_s), nc = sigm(ne*inv_s);
        float alpha = (pc-nc+1e-5f)/(pc+1e-5f);
        float wi = alpha*T;
        T *= (1.f-alpha+1e-7f);
        w[i] = wi + 1e-5f;
        wsum += w[i];
        r0 = r1;
    }
    cdf[0]=0.f;
    float c=0.f;
    for (int i=0;i<S-1;i++){ c += w[i]/wsum; cdf[i+1]=c; }
    for (int j=0;j<16;j++){
        float u = 0.03125f + 0.0625f*(float)j;
        int lo=0, hi=S;
        while (lo<hi){ int m=(lo+hi)>>1; if (cdf[m]<=u) lo=m+1; else hi=m; }
        int idx = lo;
        int below = idx-1; if (below<0) below=0; if (below>S-1) below=S-1;
        int above = idx;   if (above>S-1) above=S-1;
        float c0=cdf[below], c1=cdf[above];
        float b0=zr[below], b1=zr[above];
        float dn = c1-c0; if (dn<1e-5f) dn=1.f;
        new_z[r*16+j] = b0 + (u-c0)/dn*(b1-b0);
    }
}

__global__ void k_merge(const float* __restrict__ zin, const float* __restrict__ sin_,
                        const float* __restrict__ nz, const float* __restrict__ nsdf,
                        int S, float* __restrict__ zout, float* __restrict__ sout)
{
    int r = blockIdx.x*64+threadIdx.x; if (r>=NR) return;
    const float* az = zin + r*128; const float* as = sin_ + r*128;
    const float* bz = nz + r*16;   const float* bs = nsdf + r*16;
    int i=0, j=0;
    for (int k=0;k<S+16;k++){
        bool takeA = (j>=16) || (i<S && az[i] <= bz[j]);
        if (takeA){ zout[r*128+k]=az[i]; sout[r*128+k]=as[i]; i++; }
        else      { zout[r*128+k]=bz[j]; sout[r*128+k]=bs[j]; j++; }
    }
}

__global__ void k_composite(const float* __restrict__ z, const float* __restrict__ sdfv,
                            const float* __restrict__ tcos, const float* __restrict__ rgbs,
                            const float* __restrict__ var, float* __restrict__ out)
{
    int r = blockIdx.x*64+threadIdx.x; if (r>=NR) return;
    float inv_s = expf(var[0]*10.f);
    inv_s = fminf(fmaxf(inv_s,1e-6f),1e6f);
    float T=1.f, c0=0.f, c1=0.f, c2=0.f;
    for (int sI=0;sI<128;sI++){
        float zv = z[r*128+sI];
        float dist = (sI<127)? z[r*128+sI+1]-zv : 0.03125f;
        float sd = sdfv[r*128+sI];
        float ic = fminf(tcos[r*128+sI], 0.f);
        float ep = sd - ic*dist*0.5f, en = sd + ic*dist*0.5f;
        float pc = sigm(ep*inv_s), nc = sigm(en*inv_s);
        float al = (pc-nc+1e-5f)/(pc+1e-5f);
        al = fminf(fmaxf(al,0.f),1.f);
        float wgt = al*T;
        T *= (1.f-al+1e-7f);
        c0 += wgt*rgbs[(size_t)(r*128+sI)*3+0];
        c1 += wgt*rgbs[(size_t)(r*128+sI)*3+1];
        c2 += wgt*rgbs[(size_t)(r*128+sI)*3+2];
    }
    out[3*r+0]=c0; out[3*r+1]=c1; out[3*r+2]=c2;
}

// ---------- host ----------
static inline size_t ru8(size_t x){ return (x+7)&~(size_t)7; }

extern "C" void kernel_launch(void* const* d_in, const int* in_sizes, int n_in,
                              void* d_out, int out_size, void* d_ws, size_t ws_size,
                              hipStream_t stream)
{
    const float* rays_o = (const float*)d_in[0];
    const float* rays_d = (const float*)d_in[1];
    const float* sw[9]; const float* sb[9];
    for (int l=0;l<9;l++){ sw[l]=(const float*)d_in[2+2*l]; sb[l]=(const float*)d_in[3+2*l]; }
    const float* cw0=(const float*)d_in[20]; const float* cb0=(const float*)d_in[21];
    const float* cw1=(const float*)d_in[22]; const float* cb1=(const float*)d_in[23];
    const float* cw2=(const float*)d_in[24]; const float* cb2=(const float*)d_in[25];
    const float* varp=(const float*)d_in[26];
    float* out = (float*)d_out;
    float* f = (float*)d_ws;
    size_t nf = ws_size/sizeof(float);

    size_t off = 0;
    auto AF = [&](size_t n){ float* p = f+off; off += n; return p; };
    float* zA   = AF(NR*128);
    float* zB   = AF(NR*128);
    float* sA   = AF(NR*128);
    float* sB   = AF(NR*128);
    float* nzb  = AF(NR*16);
    float* nsb  = AF(NR*16);
    float* sdfF = AF(NR*128);
    float* tcos = AF(NR*128);
    float* rgbs = AF((size_t)NR*128*3);
    float* pts  = AF((size_t)65536*3);

    // weight plane pool
    bf16* wb = (bf16*)(f+off);
    size_t wboff = 0;
    auto AB = [&](size_t n){ n = ru8(n); bf16* p = wb+wboff; wboff += n; return p; };

    const int inD[9]  = {39,256,256,256,256,256,256,256,256};
    const int outD[9] = {256,256,256,217,256,256,256,256,257};
    const bf16 *tH[11], *tL[11]; int ldt[11];
    const bf16 *nH[8]; int ldn_[8];
    ConvArgs ca;
    for (int l=0;l<9;l++){
        int K=inD[l], N=outD[l];
        int ld = (int)ru8(K);
        bf16* th = AB((size_t)N*ld);
        bf16* tl = AB((size_t)N*ld);
        bf16* nh = nullptr; int ldn = 0;
        if (l<8){ ldn = (int)ru8(N); nh = AB((size_t)K*ldn); nH[l]=nh; ldn_[l]=ldn; }
        tH[l]=th; tL[l]=tl; ldt[l]=ld;
        ca.d[l] = ConvDesc{ sw[l], th, tl, nh, K, N, ld, ldn };
    }
    {
        int K=265, N=256, ld=(int)ru8(K); // 272
        bf16* th = AB((size_t)N*ld); bf16* tl = AB((size_t)N*ld);
        tH[9]=th; tL[9]=tl; ldt[9]=ld;
        ca.d[9] = ConvDesc{ cw0, th, tl, nullptr, K, N, ld, 0 };
        K=256; N=256; ld=256;
        bf16* th1 = AB((size_t)N*ld); bf16* tl1 = AB((size_t)N*ld);
        tH[10]=th1; tL[10]=tl1; ldt[10]=ld;
        ca.d[10] = ConvDesc{ cw1, th1, tl1, nullptr, K, N, ld, 0 };
    }
    off += (wboff+1)/2;

    // chunk region
    size_t avail = (nf > off) ? nf - off : 0;
    int CHF = 131072;
    while (CHF > 1024 && (size_t)CHF*1290 > avail) CHF >>= 1;

    float* ptsl = f + off;  off += (size_t)CHF*3;
    bf16* cb2_ = (bf16*)(f+off);
    size_t bo2 = 0;
    auto B3 = [&](size_t n){ n=ru8(n); bf16* p=cb2_+bo2; bo2+=n; return p; };
    bf16* facP[8]; int facld[8];
    for (int l=0;l<8;l++){
        int ld = (l==3)? 217 : 256;
        facP[l] = B3((size_t)CHF*ld); facld[l]=ld;
    }
    bf16* cinH = B3((size_t)CHF*272);
    bf16* cinL = B3((size_t)CHF*272);

    // ---- weight conversion ----
    k_conv<<<dim3(266,11),256,0,stream>>>(ca);
    // ---- rays + base z + pts ----
    k_ray_setup<<<NR,64,0,stream>>>(rays_o, rays_d, zA);
    k_pts<<<(65536+255)/256,256,0,stream>>>(zA, 64, 128, rays_o, rays_d, pts, 65536);

    // common FwdArgs template
    FwdArgs fa{};
    for (int l=0;l<9;l++){ fa.wh[l]=tH[l]; fa.wl[l]=tL[l]; fa.wld[l]=ldt[l]; fa.bias[l]=sb[l]; }
    fa.w8col = sw[8];

    // ---- sampling: base ----
    {
        FwdArgs s = fa;
        s.pts = pts; s.sdfo = sA; s.soff=0; s.sper=64; s.sstr=128;
        k_fwd<0><<<65536/64,256,0,stream>>>(s);
    }
    // ---- 4 up-sample steps ----
    for (int it=0; it<4; it++){
        int S = 64 + 16*it;
        float* zsrc = (it&1)? zB : zA;  float* ssrc = (it&1)? sB : sA;
        float* zdst = (it&1)? zA : zB;  float* sdst = (it&1)? sA : sB;
        float inv_s = 64.f * (float)(1<<it);
        k_upsample<<<NR/64,64,0,stream>>>(rays_o, rays_d, zsrc, ssrc, S, inv_s, nzb);
        k_pts<<<(NR*16+255)/256,256,0,stream>>>(nzb, 16, 16, rays_o, rays_d, pts, NR*16);
        FwdArgs s = fa;
        s.pts = pts; s.sdfo = nsb; s.soff=0; s.sper=16; s.sstr=16;
        k_fwd<0><<<(NR*16)/64,256,0,stream>>>(s);
        k_merge<<<NR/64,64,0,stream>>>(zsrc, ssrc, nzb, nsb, S, zdst, sdst);
    }
    // final z in zA

    // ---- final phase ----
    for (int offp=0; offp<NR*128; offp+=CHF){
        int n = CHF;
        k_pts_mid<<<(n+255)/256,256,0,stream>>>(zA, rays_o, rays_d, offp, n, ptsl);
        FwdArgs s = fa;
        s.pts = ptsl; s.sdfo = sdfF; s.soff=offp; s.sper=1; s.sstr=1;
        s.cinH=cinH; s.cinL=cinL;
        for (int l=0;l<8;l++){ s.fac[l]=facP[l]; s.facld[l]=facld[l]; }
        k_fwd<1><<<n/64,256,0,stream>>>(s);

        BwdArgs b{};
        for (int l=0;l<8;l++){ b.nh[l]=nH[l]; b.ldn[l]=ldn_[l]; b.fac[l]=facP[l]; b.facld[l]=facld[l]; }
        b.w8col = sw[8]; b.pts = ptsl; b.raysd = rays_d;
        b.cinH=cinH; b.cinL=cinL; b.tcos=tcos; b.offp=offp;
        k_bwd<<<n/64,256,0,stream>>>(b);

        ColArgs c{};
        c.cinH=cinH; c.cinL=cinL;
        c.w0h=tH[9]; c.w0l=tL[9]; c.ld0=ldt[9]; c.b0=cb0;
        c.w1h=tH[10]; c.w1l=tL[10]; c.b1=cb1;
        c.w2=cw2; c.b2=cb2; c.rgb = rgbs + (size_t)offp*3;
        k_col<<<n/64,256,0,stream>>>(c);
    }
    k_composite<<<NR/64,64,0,stream>>>(zA, sdfF, tcos, rgbs, varp, out);
}

// Round 4
// 3614.188 us; speedup vs baseline: 5.6051x; 1.6509x over previous
//
#include <hip/hip_runtime.h>
#include <math.h>

#define NR 1024
#define AS 264    // fwd/bwd activation LDS stride (bf16)
#define AS2 296   // color activation LDS stride (bf16)
#define IS2 0.70710678118654752f

typedef __bf16 bf16;
typedef bf16 bf16x8 __attribute__((ext_vector_type(8)));
typedef float floatx4 __attribute__((ext_vector_type(4)));

__device__ __forceinline__ float sigm(float x){ return 1.f/(1.f+expf(-x)); }
__device__ __forceinline__ float fast_sp100(float z){
    float x = 100.f*z;
    return (fmaxf(x,0.f) + __logf(1.f + __expf(-fabsf(x)))) * 0.01f;
}
__device__ __forceinline__ float fast_sigm100(float z){
    return __builtin_amdgcn_rcpf(1.f + __expf(-100.f*z));
}

// ---------- in-kernel GEMM: acc = A_lds @ W^T, B frags loaded DIRECT from global ----------
// PASSES==3: AhBh + AlBh + AhBl ; PASSES==2: AhBh + AlBh (Wl unused)
template<int PASSES, int ASP, int NK>
__device__ __forceinline__ void mlp_gemm(
    const bf16* __restrict__ Wh, const bf16* __restrict__ Wl, int ld,
    const bf16* Ahs, const bf16* Als,
    floatx4 (&acc)[2][8], int wr, int cb, int lr, int lq)
{
    #pragma unroll
    for (int i=0;i<2;i++)
        #pragma unroll
        for (int j=0;j<8;j++) acc[i][j] = floatx4{0.f,0.f,0.f,0.f};
    const bf16* wh = Wh + (size_t)(cb+lr)*ld + lq*8;
    const bf16* wl = (PASSES==3) ? (Wl + (size_t)(cb+lr)*ld + lq*8) : nullptr;
    #pragma unroll 1
    for (int kt=0; kt<NK; kt++){
        bf16x8 bh[8];
        #pragma unroll
        for (int j=0;j<8;j++) bh[j] = *(const bf16x8*)(wh + (size_t)(j*16)*ld + kt*32);
        bf16x8 bl[8];
        if (PASSES==3){
            #pragma unroll
            for (int j=0;j<8;j++) bl[j] = *(const bf16x8*)(wl + (size_t)(j*16)*ld + kt*32);
        }
        const int ab = (wr*32+lr)*ASP + kt*32 + lq*8;
        bf16x8 a0h = *(const bf16x8*)&Ahs[ab];
        bf16x8 a1h = *(const bf16x8*)&Ahs[ab+16*ASP];
        bf16x8 a0l = *(const bf16x8*)&Als[ab];
        bf16x8 a1l = *(const bf16x8*)&Als[ab+16*ASP];
        #pragma unroll
        for (int j=0;j<8;j++){
            acc[0][j] = __builtin_amdgcn_mfma_f32_16x16x32_bf16(a0h, bh[j], acc[0][j],0,0,0);
            acc[1][j] = __builtin_amdgcn_mfma_f32_16x16x32_bf16(a1h, bh[j], acc[1][j],0,0,0);
            acc[0][j] = __builtin_amdgcn_mfma_f32_16x16x32_bf16(a0l, bh[j], acc[0][j],0,0,0);
            acc[1][j] = __builtin_amdgcn_mfma_f32_16x16x32_bf16(a1l, bh[j], acc[1][j],0,0,0);
            if (PASSES==3){
                acc[0][j] = __builtin_amdgcn_mfma_f32_16x16x32_bf16(a0h, bl[j], acc[0][j],0,0,0);
                acc[1][j] = __builtin_amdgcn_mfma_f32_16x16x32_bf16(a1h, bl[j], acc[1][j],0,0,0);
            }
        }
    }
}

// ---------- fused forward SDF MLP ----------
struct FwdArgs {
    const float* pts;
    const bf16 *wh[9], *wl[9]; int wld[9];
    const float* bias[9];
    const float* w8col;           // sw[8], stride 257 (col 0)
    float* sdfo; int soff, sper, sstr;
    bf16 *cinH, *cinL;            // MODE 1
    bf16* fac[8]; int facld[8];   // MODE 1
};

template<int MODE>  // 0 = sampling (sdf only), 1 = final (fac + cin feat + sdf)
__global__ __launch_bounds__(256,2) void k_fwd(FwdArgs a)
{
    __shared__ bf16 Ahs[64*AS], Als[64*AS];
    __shared__ float Ef[64][40];
    __shared__ float W8s[256];
    const int tid=threadIdx.x, wid=tid>>6, lane=tid&63, lr=lane&15, lq=lane>>4;
    const int wr=wid>>1, cb=(wid&1)*128;
    const int bm = blockIdx.x*64;

    W8s[tid] = a.w8col[(size_t)tid*257];
    if (tid<64){
        const float* pp = a.pts + (size_t)(bm+tid)*3;
        float p0=pp[0],p1=pp[1],p2=pp[2];
        float vals[39];
        vals[0]=p0; vals[1]=p1; vals[2]=p2;
        float fq=1.f;
        #pragma unroll
        for (int q=0;q<6;q++){
            vals[3+6*q+0]=__sinf(fq*p0); vals[3+6*q+1]=__sinf(fq*p1); vals[3+6*q+2]=__sinf(fq*p2);
            vals[3+6*q+3]=__cosf(fq*p0); vals[3+6*q+4]=__cosf(fq*p1); vals[3+6*q+5]=__cosf(fq*p2);
            fq *= 2.f;
        }
        bf16* ah=&Ahs[tid*AS]; bf16* al=&Als[tid*AS];
        #pragma unroll
        for (int j=0;j<39;j++){
            float v=vals[j]; Ef[tid][j]=v;
            bf16 h=(bf16)v; ah[j]=h; al[j]=(bf16)(v-(float)h);
        }
        #pragma unroll
        for (int j=39;j<64;j++){ ah[j]=(bf16)0.f; al[j]=(bf16)0.f; }
    }
    __syncthreads();

    floatx4 acc[2][8];
    auto wb_act = [&](const float* bias, bf16* facp, int fld, bool l3){
        #pragma unroll
        for (int i=0;i<2;i++){
            int rbase = wr*32+i*16+lq*4;
            #pragma unroll
            for (int j=0;j<8;j++){
                int col = cb+j*16+lr;
                bool ok = (!l3) || (col<217);
                float bv = ok ? bias[col] : 0.f;
                #pragma unroll
                for (int r=0;r<4;r++){
                    if (!ok) continue;
                    int row = rbase+r;
                    float v = acc[i][j][r]+bv;
                    if (MODE==1) facp[(size_t)(bm+row)*fld+col] = (bf16)fast_sigm100(v);
                    float act = fast_sp100(v); if (l3) act *= IS2;
                    bf16 h=(bf16)act;
                    Ahs[row*AS+col]=h; Als[row*AS+col]=(bf16)(act-(float)h);
                }
            }
        }
    };

    #define LAYER(L,NKV,L3F) \
        mlp_gemm<3,AS,NKV>(a.wh[L],a.wl[L],a.wld[L], Ahs,Als, acc, wr,cb,lr,lq); \
        __syncthreads(); \
        wb_act(a.bias[L], MODE? a.fac[L]:(bf16*)nullptr, (L==3)?217:256, L3F);

    LAYER(0,2,false)
    __syncthreads();
    LAYER(1,8,false)
    __syncthreads();
    LAYER(2,8,false)
    __syncthreads();
    LAYER(3,8,true)
    if (tid<64){
        bf16* ah=&Ahs[tid*AS]; bf16* al=&Als[tid*AS];
        #pragma unroll
        for (int c=217;c<256;c++){
            float v = Ef[tid][c-217]*IS2;
            bf16 h=(bf16)v; ah[c]=h; al[c]=(bf16)(v-(float)h);
        }
    }
    __syncthreads();
    LAYER(4,8,false)
    __syncthreads();
    LAYER(5,8,false)
    __syncthreads();
    LAYER(6,8,false)
    __syncthreads();
    LAYER(7,8,false)
    __syncthreads();
    #undef LAYER

    if (MODE==1){
        // L8 feat: cols 1..256 of W8 -> cin cols 9..264
        mlp_gemm<3,AS,8>(a.wh[8]+a.wld[8], a.wl[8]+a.wld[8], a.wld[8],
                         Ahs,Als, acc, wr,cb,lr,lq);
        #pragma unroll
        for (int i=0;i<2;i++){
            int rbase = wr*32+i*16+lq*4;
            #pragma unroll
            for (int j=0;j<8;j++){
                int col = cb+j*16+lr;
                float bv = a.bias[8][1+col];
                #pragma unroll
                for (int r=0;r<4;r++){
                    int row = rbase+r;
                    float v = acc[i][j][r]+bv;
                    bf16 h=(bf16)v;
                    a.cinH[(size_t)(bm+row)*272 + 9+col]=h;
                    a.cinL[(size_t)(bm+row)*272 + 9+col]=(bf16)(v-(float)h);
                }
            }
        }
    }
    // sdf = h7 . W8[:,0] + b8[0]
    {
        int row = wid*16+lr;
        const bf16* ah=&Ahs[row*AS+lq*64]; const bf16* al=&Als[row*AS+lq*64];
        float s=0.f;
        #pragma unroll
        for (int c=0;c<8;c++){
            bf16x8 vh=*(const bf16x8*)(ah+c*8), vl=*(const bf16x8*)(al+c*8);
            #pragma unroll
            for (int j=0;j<8;j++) s += ((float)vh[j]+(float)vl[j]) * W8s[lq*64+c*8+j];
        }
        s += __shfl_xor(s,16,64); s += __shfl_xor(s,32,64);
        if (lq==0){
            int p = a.soff + bm + row;
            a.sdfo[(p/a.sper)*a.sstr + (p%a.sper)] = s + a.bias[8][0];
        }
    }
}

// ---------- fused backward (sdf grad wrt pts) + emb_bwd ----------
struct BwdArgs {
    const bf16* nh[8]; int ldn[8];
    const bf16* fac[8]; int facld[8];
    const float* w8col;
    const float* pts; const float* raysd;
    bf16 *cinH, *cinL;
    float* tcos; int offp;
};

__global__ __launch_bounds__(256,2) void k_bwd(BwdArgs a)
{
    __shared__ bf16 Ahs[64*AS], Als[64*AS];
    __shared__ float detl[64][40];
    __shared__ float W8s[256];
    float* dn0 = (float*)Als;   // aliased AFTER the last gemm
    const int tid=threadIdx.x, wid=tid>>6, lane=tid&63, lr=lane&15, lq=lane>>4;
    const int wr=wid>>1, cb=(wid&1)*128;
    const int bm = blockIdx.x*64;

    W8s[tid] = a.w8col[(size_t)tid*257];
    __syncthreads();
    // dZ7 = W8[:,0] * fac7  (vectorized: thread -> row tid&63, col block (tid>>6)*64)
    {
        int row = tid&63, c0 = (tid>>6)*64;
        const bf16* f7 = a.fac[7] + (size_t)(bm+row)*256 + c0;
        bf16* ah=&Ahs[row*AS+c0]; bf16* al=&Als[row*AS+c0];
        #pragma unroll
        for (int c=0;c<64;c+=8){
            bf16x8 fv = *(const bf16x8*)(f7+c);
            bf16x8 hv, lv;
            #pragma unroll
            for (int j=0;j<8;j++){
                float v = W8s[c0+c+j]*(float)fv[j];
                bf16 h=(bf16)v; hv[j]=h; lv[j]=(bf16)(v-(float)h);
            }
            *(bf16x8*)(ah+c)=hv; *(bf16x8*)(al+c)=lv;
        }
    }
    __syncthreads();

    floatx4 acc[2][8];
    auto wb_fac = [&](const bf16* fc, int fld){
        #pragma unroll
        for (int i=0;i<2;i++){
            int rbase = wr*32+i*16+lq*4;
            #pragma unroll
            for (int j=0;j<8;j++){
                int col = cb+j*16+lr;
                #pragma unroll
                for (int r=0;r<4;r++){
                    int row = rbase+r;
                    float v = acc[i][j][r] * (float)fc[(size_t)(bm+row)*fld+col];
                    bf16 h=(bf16)v;
                    Ahs[row*AS+col]=h; Als[row*AS+col]=(bf16)(v-(float)h);
                }
            }
        }
    };

    #define BLAYER(L,NKV,FC,FLD) \
        mlp_gemm<2,AS,NKV>(a.nh[L],nullptr,a.ldn[L], Ahs,Als, acc, wr,cb,lr,lq); \
        __syncthreads(); \
        wb_fac(FC,FLD); \
        __syncthreads();

    BLAYER(7,8,a.fac[6],256)
    BLAYER(6,8,a.fac[5],256)
    BLAYER(5,8,a.fac[4],256)
    // din4 -> split
    mlp_gemm<2,AS,8>(a.nh[4],nullptr,a.ldn[4], Ahs,Als, acc, wr,cb,lr,lq);
    __syncthreads();
    #pragma unroll
    for (int i=0;i<2;i++){
        int rbase = wr*32+i*16+lq*4;
        #pragma unroll
        for (int j=0;j<8;j++){
            int col = cb+j*16+lr;
            #pragma unroll
            for (int r=0;r<4;r++){
                int row = rbase+r;
                float v = acc[i][j][r]*IS2;
                if (col<217){
                    v *= (float)a.fac[3][(size_t)(bm+row)*217+col];
                    bf16 h=(bf16)v;
                    Ahs[row*AS+col]=h; Als[row*AS+col]=(bf16)(v-(float)h);
                } else {
                    detl[row][col-217]=v;
                    Ahs[row*AS+col]=(bf16)0.f; Als[row*AS+col]=(bf16)0.f;
                }
            }
        }
    }
    __syncthreads();
    BLAYER(3,7,a.fac[2],256)
    BLAYER(2,8,a.fac[1],256)
    BLAYER(1,8,a.fac[0],256)
    #undef BLAYER
    // din0 (N=39)
    mlp_gemm<2,AS,8>(a.nh[0],nullptr,a.ldn[0], Ahs,Als, acc, wr,cb,lr,lq);
    __syncthreads();   // all waves done reading Als -> safe to alias as dn0
    #pragma unroll
    for (int i=0;i<2;i++){
        int rbase = wr*32+i*16+lq*4;
        #pragma unroll
        for (int j=0;j<8;j++){
            int col = cb+j*16+lr;
            if (col<39){
                #pragma unroll
                for (int r=0;r<4;r++) dn0[(rbase+r)*40+col] = acc[i][j][r];
            }
        }
    }
    __syncthreads();
    if (tid<64){
        int p = a.offp + bm + tid;
        int rI = p>>7;
        const float* pp = a.pts + (size_t)(bm+tid)*3;
        float px=pp[0],py=pp[1],pz=pp[2];
        float g0=dn0[tid*40+0]+detl[tid][0];
        float g1=dn0[tid*40+1]+detl[tid][1];
        float g2=dn0[tid*40+2]+detl[tid][2];
        float fq=1.f;
        #pragma unroll
        for (int q=0;q<6;q++){
            int base=3+6*q;
            float ds0=dn0[tid*40+base+0]+detl[tid][base+0];
            float ds1=dn0[tid*40+base+1]+detl[tid][base+1];
            float ds2=dn0[tid*40+base+2]+detl[tid][base+2];
            float dc0=dn0[tid*40+base+3]+detl[tid][base+3];
            float dc1=dn0[tid*40+base+4]+detl[tid][base+4];
            float dc2=dn0[tid*40+base+5]+detl[tid][base+5];
            g0 += fq*(__cosf(fq*px)*ds0 - __sinf(fq*px)*dc0);
            g1 += fq*(__cosf(fq*py)*ds1 - __sinf(fq*py)*dc1);
            g2 += fq*(__cosf(fq*pz)*ds2 - __sinf(fq*pz)*dc2);
            fq *= 2.f;
        }
        float dx=a.raysd[3*rI],dy=a.raysd[3*rI+1],dz=a.raysd[3*rI+2];
        a.tcos[p] = dx*g0+dy*g1+dz*g2;
        float nm = fmaxf(sqrtf(g0*g0+g1*g1+g2*g2), 1e-6f);
        float vals[9] = {px,py,pz,dx,dy,dz,g0/nm,g1/nm,g2/nm};
        bf16* ch = a.cinH + (size_t)(bm+tid)*272;
        bf16* cl = a.cinL + (size_t)(bm+tid)*272;
        #pragma unroll
        for (int c=0;c<9;c++){
            float v=vals[c]; bf16 h=(bf16)v;
            ch[c]=h; cl[c]=(bf16)(v-(float)h);
        }
        #pragma unroll
        for (int c=265;c<272;c++){ ch[c]=(bf16)0.f; cl[c]=(bf16)0.f; }
    }
}

// ---------- fused color MLP ----------
struct ColArgs {
    const bf16 *cinH, *cinL;
    const bf16 *w0h,*w0l; int ld0; const float* b0;
    const bf16 *w1h,*w1l; const float* b1;
    const float* w2; const float* b2;
    float* rgb;
};

__global__ __launch_bounds__(256,2) void k_col(ColArgs a)
{
    __shared__ bf16 Ahs[64*AS2], Als[64*AS2];
    __shared__ float W2s[256*3];
    const int tid=threadIdx.x, wid=tid>>6, lane=tid&63, lr=lane&15, lq=lane>>4;
    const int wr=wid>>1, cb=(wid&1)*128;
    const int bm = blockIdx.x*64;

    W2s[tid*3]=a.w2[tid*3]; W2s[tid*3+1]=a.w2[tid*3+1]; W2s[tid*3+2]=a.w2[tid*3+2];
    // stage cin (hi/lo) into LDS
    {
        int row = tid&63, part = tid>>6;
        const bf16* src = (part&2)? a.cinL : a.cinH;
        bf16* dst = (part&2)? Als : Ahs;
        int c0 = (part&1)*136;
        const bf16* s = src + (size_t)(bm+row)*272 + c0;
        bf16* d = dst + row*AS2 + c0;
        #pragma unroll
        for (int v=0;v<17;v++) *(bf16x8*)(d+v*8) = *(const bf16x8*)(s+v*8);
        if (part&1){
            bf16x8 z = {};
            bf16* zd = dst + row*AS2 + 272;
            #pragma unroll
            for (int v=0;v<3;v++) *(bf16x8*)(zd+v*8) = z;
        }
    }
    __syncthreads();

    floatx4 acc[2][8];
    auto wb_relu = [&](const float* bias){
        #pragma unroll
        for (int i=0;i<2;i++){
            int rbase = wr*32+i*16+lq*4;
            #pragma unroll
            for (int j=0;j<8;j++){
                int col = cb+j*16+lr;
                float bv = bias[col];
                #pragma unroll
                for (int r=0;r<4;r++){
                    int row = rbase+r;
                    float v = fmaxf(acc[i][j][r]+bv, 0.f);
                    bf16 h=(bf16)v;
                    Ahs[row*AS2+col]=h; Als[row*AS2+col]=(bf16)(v-(float)h);
                }
            }
        }
    };
    mlp_gemm<3,AS2,9>(a.w0h,a.w0l,a.ld0, Ahs,Als, acc, wr,cb,lr,lq);
    __syncthreads();
    wb_relu(a.b0);
    __syncthreads();
    mlp_gemm<3,AS2,8>(a.w1h,a.w1l,256, Ahs,Als, acc, wr,cb,lr,lq);
    __syncthreads();
    wb_relu(a.b1);
    __syncthreads();
    // rgb = sigmoid(h @ cw2 + cb2)
    {
        int row = wid*16+lr;
        const bf16* ah=&Ahs[row*AS2+lq*64]; const bf16* al=&Als[row*AS2+lq*64];
        float s0=0.f,s1=0.f,s2=0.f;
        #pragma unroll
        for (int c=0;c<8;c++){
            bf16x8 vh=*(const bf16x8*)(ah+c*8), vl=*(const bf16x8*)(al+c*8);
            #pragma unroll
            for (int j=0;j<8;j++){
                float f = (float)vh[j]+(float)vl[j];
                int k = lq*64+c*8+j;
                s0 += f*W2s[k*3]; s1 += f*W2s[k*3+1]; s2 += f*W2s[k*3+2];
            }
        }
        s0 += __shfl_xor(s0,16,64); s0 += __shfl_xor(s0,32,64);
        s1 += __shfl_xor(s1,16,64); s1 += __shfl_xor(s1,32,64);
        s2 += __shfl_xor(s2,16,64); s2 += __shfl_xor(s2,32,64);
        if (lq==0){
            float* o = a.rgb + (size_t)(bm+row)*3;
            o[0]=sigm(s0+a.b2[0]); o[1]=sigm(s1+a.b2[1]); o[2]=sigm(s2+a.b2[2]);
        }
    }
}

// ---------- weight conversion ----------
struct ConvDesc { const float* src; bf16 *th, *tl, *nh; int K, N, ldt, ldn; };
struct ConvArgs { ConvDesc d[11]; };
__global__ void k_conv(ConvArgs a){
    ConvDesc cd = a.d[blockIdx.y];
    int idx = blockIdx.x*256+threadIdx.x;
    if (idx >= cd.K*cd.N) return;
    int k = idx / cd.N, n = idx - k*cd.N;
    float v = cd.src[idx];
    bf16 h = (bf16)v;
    cd.th[(size_t)n*cd.ldt + k] = h;
    cd.tl[(size_t)n*cd.ldt + k] = (bf16)(v - (float)h);
    if (cd.nh) cd.nh[(size_t)k*cd.ldn + n] = h;
}

// ---------- small kernels ----------
__global__ void k_ray_setup(const float* __restrict__ o, const float* __restrict__ d,
                            float* __restrict__ z)
{
    int r = blockIdx.x; int i = threadIdx.x;
    float ox=o[3*r],oy=o[3*r+1],oz=o[3*r+2];
    float dx=d[3*r],dy=d[3*r+1],dz=d[3*r+2];
    float a = dx*dx+dy*dy+dz*dz;
    float b = 2.f*(ox*dx+oy*dy+oz*dz);
    float mid = -b/(2.f*a);
    float nearv = fmaxf(mid-1.f, 0.05f);
    float farv = mid+1.f;
    z[r*128+i] = nearv + (farv-nearv)*((float)i/63.f);
}

__global__ void k_pts(const float* __restrict__ zbuf, int per_ray, int stride,
                      const float* __restrict__ o, const float* __restrict__ d,
                      float* __restrict__ pts, int np)
{
    int i = blockIdx.x*256+threadIdx.x; if (i>=np) return;
    int r = i/per_ray, k = i%per_ray;
    float z = zbuf[r*stride+k];
    pts[3*i+0] = o[3*r+0]+d[3*r+0]*z;
    pts[3*i+1] = o[3*r+1]+d[3*r+1]*z;
    pts[3*i+2] = o[3*r+2]+d[3*r+2]*z;
}

__global__ void k_pts_mid(const float* __restrict__ z, const float* __restrict__ o,
                          const float* __restrict__ d, int off, int n,
                          float* __restrict__ pts)
{
    int i = blockIdx.x*256+threadIdx.x; if (i>=n) return;
    int p = off+i; int r = p>>7; int sI = p&127;
    float zv = z[r*128+sI];
    float dist = (sI<127) ? z[r*128+sI+1]-zv : 0.03125f;
    float mid = zv + 0.5f*dist;
    pts[3*i+0]=o[3*r+0]+d[3*r+0]*mid;
    pts[3*i+1]=o[3*r+1]+d[3*r+1]*mid;
    pts[3*i+2]=o[3*r+2]+d[3*r+2]*mid;
}

__global__ void k_upsample(const float* __restrict__ o, const float* __restrict__ d,
                           const float* __restrict__ z, const float* __restrict__ sdf,
                           int S, float inv_s, float* __restrict__ new_z)
{
    int r = blockIdx.x*64+threadIdx.x; if (r>=NR) return;
    const float* zr = z + r*128;
    const float* sr = sdf + r*128;
    float ox=o[3*r],oy=o[3*r+1],oz=o[3*r+2];
    float dx=d[3*r],dy=d[3*r+1],dz=d[3*r+2];
    float w[128];
    float cdf[129];
    float wsum=0.f, T=1.f, raw_prev=0.f;
    float z0 = zr[0];
    float px=ox+dx*z0, py=oy+dy*z0, pz=oz+dz*z0;
    float r0 = sqrtf(px*px+py*py+pz*pz);
    for (int i=0;i<S-1;i++){
        float z1 = zr[i+1];
        float qx=ox+dx*z1, qy=oy+dy*z1, qz=oz+dz*z1;
        float r1 = sqrtf(qx*qx+qy*qy+qz*qz);
        bool inside = (r0<1.f)||(r1<1.f);
        float s0=sr[i], s1=sr[i+1];
        float zc = zr[i];
        float mid_sdf = 0.5f*(s0+s1);
        float raw = (s1-s0)/(z1-zc+1e-5f);
        float cv = fminf(raw, (i==0)?0.f:raw_prev);
        raw_prev = raw;
        cv = fminf(fmaxf(cv,-1000.f),0.f);
        if (!inside) cv = 0.f;
        float dist = z1-zc;
        float pe = mid_sdf - cv*dist*0.5f;
        float ne = mid_sdf + cv*dist*0.5f;
        float pc = sigm(pe*inv_s), nc = sigm(ne*inv_s);
        float alpha = (pc-nc+1e-5f)/(pc+1e-5f);
        float wi = alpha*T;
        T *= (1.f-alpha+1e-7f);
        w[i] = wi + 1e-5f;
        wsum += w[i];
        r0 = r1;
    }
    cdf[0]=0.f;
    float c=0.f;
    for (int i=0;i<S-1;i++){ c += w[i]/wsum; cdf[i+1]=c; }
    for (int j=0;j<16;j++){
        float u = 0.03125f + 0.0625f*(float)j;
        int lo=0, hi=S;
        while (lo<hi){ int m=(lo+hi)>>1; if (cdf[m]<=u) lo=m+1; else hi=m; }
        int idx = lo;
        int below = idx-1; if (below<0) below=0; if (below>S-1) below=S-1;
        int above = idx;   if (above>S-1) above=S-1;
        float c0=cdf[below], c1=cdf[above];
        float b0=zr[below], b1=zr[above];
        float dn = c1-c0; if (dn<1e-5f) dn=1.f;
        new_z[r*16+j] = b0 + (u-c0)/dn*(b1-b0);
    }
}

__global__ void k_merge(const float* __restrict__ zin, const float* __restrict__ sin_,
                        const float* __restrict__ nz, const float* __restrict__ nsdf,
                        int S, float* __restrict__ zout, float* __restrict__ sout)
{
    int r = blockIdx.x*64+threadIdx.x; if (r>=NR) return;
    const float* az = zin + r*128; const float* as = sin_ + r*128;
    const float* bz = nz + r*16;   const float* bs = nsdf + r*16;
    int i=0, j=0;
    for (int k=0;k<S+16;k++){
        bool takeA = (j>=16) || (i<S && az[i] <= bz[j]);
        if (takeA){ zout[r*128+k]=az[i]; sout[r*128+k]=as[i]; i++; }
        else      { zout[r*128+k]=bz[j]; sout[r*128+k]=bs[j]; j++; }
    }
}

__global__ void k_composite(const float* __restrict__ z, const float* __restrict__ sdfv,
                            const float* __restrict__ tcos, const float* __restrict__ rgbs,
                            const float* __restrict__ var, float* __restrict__ out)
{
    int r = blockIdx.x*64+threadIdx.x; if (r>=NR) return;
    float inv_s = expf(var[0]*10.f);
    inv_s = fminf(fmaxf(inv_s,1e-6f),1e6f);
    float T=1.f, c0=0.f, c1=0.f, c2=0.f;
    for (int sI=0;sI<128;sI++){
        float zv = z[r*128+sI];
        float dist = (sI<127)? z[r*128+sI+1]-zv : 0.03125f;
        float sd = sdfv[r*128+sI];
        float ic = fminf(tcos[r*128+sI], 0.f);
        float ep = sd - ic*dist*0.5f, en = sd + ic*dist*0.5f;
        float pc = sigm(ep*inv_s), nc = sigm(en*inv_s);
        float al = (pc-nc+1e-5f)/(pc+1e-5f);
        al = fminf(fmaxf(al,0.f),1.f);
        float wgt = al*T;
        T *= (1.f-al+1e-7f);
        c0 += wgt*rgbs[(size_t)(r*128+sI)*3+0];
        c1 += wgt*rgbs[(size_t)(r*128+sI)*3+1];
        c2 += wgt*rgbs[(size_t)(r*128+sI)*3+2];
    }
    out[3*r+0]=c0; out[3*r+1]=c1; out[3*r+2]=c2;
}

// ---------- host ----------
static inline size_t ru8(size_t x){ return (x+7)&~(size_t)7; }

extern "C" void kernel_launch(void* const* d_in, const int* in_sizes, int n_in,
                              void* d_out, int out_size, void* d_ws, size_t ws_size,
                              hipStream_t stream)
{
    const float* rays_o = (const float*)d_in[0];
    const float* rays_d = (const float*)d_in[1];
    const float* sw[9]; const float* sb[9];
    for (int l=0;l<9;l++){ sw[l]=(const float*)d_in[2+2*l]; sb[l]=(const float*)d_in[3+2*l]; }
    const float* cw0=(const float*)d_in[20]; const float* cb0=(const float*)d_in[21];
    const float* cw1=(const float*)d_in[22]; const float* cb1=(const float*)d_in[23];
    const float* cw2=(const float*)d_in[24]; const float* cb2=(const float*)d_in[25];
    const float* varp=(const float*)d_in[26];
    float* out = (float*)d_out;
    float* f = (float*)d_ws;
    size_t nf = ws_size/sizeof(float);

    size_t off = 0;
    auto AF = [&](size_t n){ float* p = f+off; off += n; return p; };
    float* zA   = AF(NR*128);
    float* zB   = AF(NR*128);
    float* sA   = AF(NR*128);
    float* sB   = AF(NR*128);
    float* nzb  = AF(NR*16);
    float* nsb  = AF(NR*16);
    float* sdfF = AF(NR*128);
    float* tcos = AF(NR*128);
    float* rgbs = AF((size_t)NR*128*3);
    float* pts  = AF((size_t)65536*3);

    off = (off+3)&~(size_t)3;   // 16B-align the bf16 pool
    bf16* wb = (bf16*)(f+off);
    size_t wboff = 0;
    auto AB = [&](size_t n){ n = ru8(n)+32; bf16* p = wb+wboff; wboff += n; return p; };

    const int inD[9]  = {39,256,256,256,256,256,256,256,256};
    const int outD[9] = {256,256,256,217,256,256,256,256,257};
    const bf16 *tH[11], *tL[11]; int ldt[11];
    const bf16 *nH[8]; int ldn_[8];
    ConvArgs ca;
    for (int l=0;l<9;l++){
        int K=inD[l], N=outD[l];
        int ld = (int)ru8(K);
        bf16* th = AB((size_t)N*ld);
        bf16* tl = AB((size_t)N*ld);
        bf16* nh = nullptr; int ldn = 0;
        if (l<8){ ldn = (int)ru8(N); nh = AB((size_t)K*ldn); nH[l]=nh; ldn_[l]=ldn; }
        tH[l]=th; tL[l]=tl; ldt[l]=ld;
        ca.d[l] = ConvDesc{ sw[l], th, tl, nh, K, N, ld, ldn };
    }
    {
        int K=265, N=256, ld=(int)ru8(K); // 272
        bf16* th = AB((size_t)N*ld); bf16* tl = AB((size_t)N*ld);
        tH[9]=th; tL[9]=tl; ldt[9]=ld;
        ca.d[9] = ConvDesc{ cw0, th, tl, nullptr, K, N, ld, 0 };
        K=256; N=256; ld=256;
        bf16* th1 = AB((size_t)N*ld); bf16* tl1 = AB((size_t)N*ld);
        tH[10]=th1; tL[10]=tl1; ldt[10]=ld;
        ca.d[10] = ConvDesc{ cw1, th1, tl1, nullptr, K, N, ld, 0 };
    }
    off += (wboff+1)/2;
    off = (off+3)&~(size_t)3;

    // chunk region
    size_t avail = (nf > off) ? nf - off : 0;
    int CHF = 131072;
    while (CHF > 1024 && (size_t)CHF*1290 > avail) CHF >>= 1;

    float* ptsl = f + off;  off += (size_t)CHF*3;
    bf16* cb2_ = (bf16*)(f+off);
    size_t bo2 = 0;
    auto B3 = [&](size_t n){ n=ru8(n); bf16* p=cb2_+bo2; bo2+=n; return p; };
    bf16* facP[8]; int facld[8];
    for (int l=0;l<8;l++){
        int ld = (l==3)? 217 : 256;
        facP[l] = B3((size_t)CHF*ld); facld[l]=ld;
    }
    bf16* cinH = B3((size_t)CHF*272);
    bf16* cinL = B3((size_t)CHF*272);

    // ---- weight conversion ----
    k_conv<<<dim3(266,11),256,0,stream>>>(ca);
    // ---- rays + base z + pts ----
    k_ray_setup<<<NR,64,0,stream>>>(rays_o, rays_d, zA);
    k_pts<<<(65536+255)/256,256,0,stream>>>(zA, 64, 128, rays_o, rays_d, pts, 65536);

    FwdArgs fa{};
    for (int l=0;l<9;l++){ fa.wh[l]=tH[l]; fa.wl[l]=tL[l]; fa.wld[l]=ldt[l]; fa.bias[l]=sb[l]; }
    fa.w8col = sw[8];

    // ---- sampling: base ----
    {
        FwdArgs s = fa;
        s.pts = pts; s.sdfo = sA; s.soff=0; s.sper=64; s.sstr=128;
        k_fwd<0><<<65536/64,256,0,stream>>>(s);
    }
    // ---- 4 up-sample steps ----
    for (int it=0; it<4; it++){
        int S = 64 + 16*it;
        float* zsrc = (it&1)? zB : zA;  float* ssrc = (it&1)? sB : sA;
        float* zdst = (it&1)? zA : zB;  float* sdst = (it&1)? sA : sB;
        float inv_s = 64.f * (float)(1<<it);
        k_upsample<<<NR/64,64,0,stream>>>(rays_o, rays_d, zsrc, ssrc, S, inv_s, nzb);
        k_pts<<<(NR*16+255)/256,256,0,stream>>>(nzb, 16, 16, rays_o, rays_d, pts, NR*16);
        FwdArgs s = fa;
        s.pts = pts; s.sdfo = nsb; s.soff=0; s.sper=16; s.sstr=16;
        k_fwd<0><<<(NR*16)/64,256,0,stream>>>(s);
        k_merge<<<NR/64,64,0,stream>>>(zsrc, ssrc, nzb, nsb, S, zdst, sdst);
    }
    // final z in zA

    // ---- final phase ----
    for (int offp=0; offp<NR*128; offp+=CHF){
        int n = CHF;
        k_pts_mid<<<(n+255)/256,256,0,stream>>>(zA, rays_o, rays_d, offp, n, ptsl);
        FwdArgs s = fa;
        s.pts = ptsl; s.sdfo = sdfF; s.soff=offp; s.sper=1; s.sstr=1;
        s.cinH=cinH; s.cinL=cinL;
        for (int l=0;l<8;l++){ s.fac[l]=facP[l]; s.facld[l]=facld[l]; }
        k_fwd<1><<<n/64,256,0,stream>>>(s);

        BwdArgs b{};
        for (int l=0;l<8;l++){ b.nh[l]=nH[l]; b.ldn[l]=ldn_[l]; b.fac[l]=facP[l]; b.facld[l]=facld[l]; }
        b.w8col = sw[8]; b.pts = ptsl; b.raysd = rays_d;
        b.cinH=cinH; b.cinL=cinL; b.tcos=tcos; b.offp=offp;
        k_bwd<<<n/64,256,0,stream>>>(b);

        ColArgs c{};
        c.cinH=cinH; c.cinL=cinL;
        c.w0h=tH[9]; c.w0l=tL[9]; c.ld0=ldt[9]; c.b0=cb0;
        c.w1h=tH[10]; c.w1l=tL[10]; c.b1=cb1;
        c.w2=cw2; c.b2=cb2; c.rgb = rgbs + (size_t)offp*3;
        k_col<<<n/64,256,0,stream>>>(c);
    }
    k_composite<<<NR/64,64,0,stream>>>(zA, sdfF, tcos, rgbs, varp, out);
}

// Round 5
// 3597.551 us; speedup vs baseline: 5.6311x; 1.0046x over previous
//
#include <hip/hip_runtime.h>
#include <math.h>

#define NR 1024
#define AS 264    // fwd/bwd activation LDS stride (bf16)
#define AS2 296   // color activation LDS stride (bf16)
#define IS2 0.70710678118654752f

typedef __bf16 bf16;
typedef bf16 bf16x8 __attribute__((ext_vector_type(8)));
typedef float floatx4 __attribute__((ext_vector_type(4)));

__device__ __forceinline__ float sigm(float x){ return 1.f/(1.f+expf(-x)); }
__device__ __forceinline__ float fast_sp100(float z){
    float x = 100.f*z;
    return (fmaxf(x,0.f) + __logf(1.f + __expf(-fabsf(x)))) * 0.01f;
}
__device__ __forceinline__ float fast_sigm100(float z){
    return __builtin_amdgcn_rcpf(1.f + __expf(-100.f*z));
}

// ---------- in-kernel GEMM: acc = A_lds @ W^T, B frags loaded DIRECT from global ----------
// 8 waves: wave computes 32 rows (wr) x 64 cols (cb). PASSES 3 = AhBh+AlBh+AhBl; 2 = AhBh+AlBh.
template<int PASSES, int ASP, int NK>
__device__ __forceinline__ void mlp_gemm(
    const bf16* __restrict__ Wh, const bf16* __restrict__ Wl, int ld,
    const bf16* Ahs, const bf16* Als,
    floatx4 (&acc)[2][4], int wr, int cb, int lr, int lq)
{
    #pragma unroll
    for (int i=0;i<2;i++)
        #pragma unroll
        for (int j=0;j<4;j++) acc[i][j] = floatx4{0.f,0.f,0.f,0.f};
    const bf16* wh = Wh + (size_t)(cb+lr)*ld + lq*8;
    const bf16* wl = (PASSES==3) ? (Wl + (size_t)(cb+lr)*ld + lq*8) : nullptr;
    #pragma unroll 2
    for (int kt=0; kt<NK; kt++){
        bf16x8 bh[4];
        #pragma unroll
        for (int j=0;j<4;j++) bh[j] = *(const bf16x8*)(wh + (size_t)(j*16)*ld + kt*32);
        bf16x8 bl[4];
        if (PASSES==3){
            #pragma unroll
            for (int j=0;j<4;j++) bl[j] = *(const bf16x8*)(wl + (size_t)(j*16)*ld + kt*32);
        }
        const int ab = (wr*32+lr)*ASP + kt*32 + lq*8;
        bf16x8 a0h = *(const bf16x8*)&Ahs[ab];
        bf16x8 a1h = *(const bf16x8*)&Ahs[ab+16*ASP];
        bf16x8 a0l = *(const bf16x8*)&Als[ab];
        bf16x8 a1l = *(const bf16x8*)&Als[ab+16*ASP];
        #pragma unroll
        for (int j=0;j<4;j++){
            acc[0][j] = __builtin_amdgcn_mfma_f32_16x16x32_bf16(a0h, bh[j], acc[0][j],0,0,0);
            acc[1][j] = __builtin_amdgcn_mfma_f32_16x16x32_bf16(a1h, bh[j], acc[1][j],0,0,0);
            acc[0][j] = __builtin_amdgcn_mfma_f32_16x16x32_bf16(a0l, bh[j], acc[0][j],0,0,0);
            acc[1][j] = __builtin_amdgcn_mfma_f32_16x16x32_bf16(a1l, bh[j], acc[1][j],0,0,0);
            if (PASSES==3){
                acc[0][j] = __builtin_amdgcn_mfma_f32_16x16x32_bf16(a0h, bl[j], acc[0][j],0,0,0);
                acc[1][j] = __builtin_amdgcn_mfma_f32_16x16x32_bf16(a1h, bl[j], acc[1][j],0,0,0);
            }
        }
    }
}

// ---------- fused forward SDF MLP (embed fused; pts computed from z+rays in-kernel) ----------
struct FwdArgs {
    const float* zbuf; int zper, zstr, pmode;   // pmode 0: z=zbuf[r*zstr+k]; 1: midpoint from z (stride 128)
    const float *ro, *rd;
    const bf16 *wh[9], *wl[9]; int wld[9];
    const float* bias[9];
    const float* w8col;           // sw[8], stride 257 (col 0)
    float* sdfo; int soff, sper, sstr;
    bf16 *cinH, *cinL;            // MODE 1
    bf16* fac[8];                 // MODE 1
};

template<int MODE>  // 0 = sampling (sdf only), 1 = final (fac + cin feat + sdf)
__global__ __launch_bounds__(512,4) void k_fwd(FwdArgs a)
{
    __shared__ bf16 Ahs[64*AS], Als[64*AS];
    __shared__ float Ef[64][40];
    __shared__ float W8s[256];
    const int tid=threadIdx.x, wid=tid>>6, lane=tid&63, lr=lane&15, lq=lane>>4;
    const int wr=wid>>2, cb=(wid&3)*64;
    const int bm = blockIdx.x*64;

    if (tid<256) W8s[tid] = a.w8col[(size_t)tid*257];
    if (tid<64){
        int pg = a.soff + bm + tid;
        int r; float pm;
        if (a.pmode==0){
            r = pg / a.zper; int k = pg - r*a.zper;
            pm = a.zbuf[(size_t)r*a.zstr + k];
        } else {
            r = pg>>7; int sI = pg&127;
            float zv = a.zbuf[r*128+sI];
            float dist = (sI<127) ? a.zbuf[r*128+sI+1]-zv : 0.03125f;
            pm = zv + 0.5f*dist;
        }
        float p0 = a.ro[3*r+0]+a.rd[3*r+0]*pm;
        float p1 = a.ro[3*r+1]+a.rd[3*r+1]*pm;
        float p2 = a.ro[3*r+2]+a.rd[3*r+2]*pm;
        float vals[39];
        vals[0]=p0; vals[1]=p1; vals[2]=p2;
        float fq=1.f;
        #pragma unroll
        for (int q=0;q<6;q++){
            vals[3+6*q+0]=__sinf(fq*p0); vals[3+6*q+1]=__sinf(fq*p1); vals[3+6*q+2]=__sinf(fq*p2);
            vals[3+6*q+3]=__cosf(fq*p0); vals[3+6*q+4]=__cosf(fq*p1); vals[3+6*q+5]=__cosf(fq*p2);
            fq *= 2.f;
        }
        bf16* ah=&Ahs[tid*AS]; bf16* al=&Als[tid*AS];
        #pragma unroll
        for (int j=0;j<39;j++){
            float v=vals[j]; Ef[tid][j]=v;
            bf16 h=(bf16)v; ah[j]=h; al[j]=(bf16)(v-(float)h);
        }
        #pragma unroll
        for (int j=39;j<64;j++){ ah[j]=(bf16)0.f; al[j]=(bf16)0.f; }
    }
    __syncthreads();

    floatx4 acc[2][4];
    auto wb_act = [&](const float* bias, bf16* facp, int fld, bool l3){
        #pragma unroll
        for (int i=0;i<2;i++){
            int rbase = wr*32+i*16+lq*4;
            #pragma unroll
            for (int j=0;j<4;j++){
                int col = cb+j*16+lr;
                bool ok = (!l3) || (col<217);
                float bv = ok ? bias[col] : 0.f;
                #pragma unroll
                for (int r=0;r<4;r++){
                    if (!ok) continue;
                    int row = rbase+r;
                    float v = acc[i][j][r]+bv;
                    if (MODE==1) facp[(size_t)(bm+row)*fld+col] = (bf16)fast_sigm100(v);
                    float act = fast_sp100(v); if (l3) act *= IS2;
                    bf16 h=(bf16)act;
                    Ahs[row*AS+col]=h; Als[row*AS+col]=(bf16)(act-(float)h);
                }
            }
        }
    };

    #define LAYER(L,NKV,L3F) \
        mlp_gemm<3,AS,NKV>(a.wh[L],a.wl[L],a.wld[L], Ahs,Als, acc, wr,cb,lr,lq); \
        __syncthreads(); \
        wb_act(a.bias[L], MODE? a.fac[L]:(bf16*)nullptr, (L==3)?217:256, L3F); \
        __syncthreads();

    LAYER(0,2,false)
    LAYER(1,8,false)
    LAYER(2,8,false)
    LAYER(3,8,true)
    if (tid<64){
        bf16* ah=&Ahs[tid*AS]; bf16* al=&Als[tid*AS];
        #pragma unroll
        for (int c=217;c<256;c++){
            float v = Ef[tid][c-217]*IS2;
            bf16 h=(bf16)v; ah[c]=h; al[c]=(bf16)(v-(float)h);
        }
    }
    __syncthreads();
    LAYER(4,8,false)
    LAYER(5,8,false)
    LAYER(6,8,false)
    LAYER(7,8,false)
    #undef LAYER

    if (MODE==1){
        // L8 feat: cols 1..256 of W8 -> cin cols 9..264
        mlp_gemm<3,AS,8>(a.wh[8]+a.wld[8], a.wl[8]+a.wld[8], a.wld[8],
                         Ahs,Als, acc, wr,cb,lr,lq);
        #pragma unroll
        for (int i=0;i<2;i++){
            int rbase = wr*32+i*16+lq*4;
            #pragma unroll
            for (int j=0;j<4;j++){
                int col = cb+j*16+lr;
                float bv = a.bias[8][1+col];
                #pragma unroll
                for (int r=0;r<4;r++){
                    int row = rbase+r;
                    float v = acc[i][j][r]+bv;
                    bf16 h=(bf16)v;
                    a.cinH[(size_t)(bm+row)*272 + 9+col]=h;
                    a.cinL[(size_t)(bm+row)*272 + 9+col]=(bf16)(v-(float)h);
                }
            }
        }
    }
    // sdf = h7 . W8[:,0] + b8[0]   (8 lanes per row)
    {
        int row = wid*8 + (lane>>3);
        int kc  = (lane&7)*32;
        const bf16* ah=&Ahs[row*AS+kc]; const bf16* al=&Als[row*AS+kc];
        float s=0.f;
        #pragma unroll
        for (int c=0;c<4;c++){
            bf16x8 vh=*(const bf16x8*)(ah+c*8), vl=*(const bf16x8*)(al+c*8);
            #pragma unroll
            for (int j=0;j<8;j++) s += ((float)vh[j]+(float)vl[j]) * W8s[kc+c*8+j];
        }
        s += __shfl_xor(s,1,64); s += __shfl_xor(s,2,64); s += __shfl_xor(s,4,64);
        if ((lane&7)==0){
            int pg = a.soff + bm + row;
            a.sdfo[(pg/a.sper)*a.sstr + (pg%a.sper)] = s + a.bias[8][0];
        }
    }
}

// ---------- fused backward (sdf grad wrt pts) + emb_bwd ----------
struct BwdArgs {
    const bf16* nh[8]; int ldn[8];
    const bf16* fac[8];
    const float* w8col;
    const float* zA; const float *ro, *rd;
    bf16 *cinH, *cinL;
    float* tcos; int offp;
};

__global__ __launch_bounds__(512,4) void k_bwd(BwdArgs a)
{
    __shared__ bf16 Ahs[64*AS], Als[64*AS];
    __shared__ float detl[64][40];
    __shared__ float W8s[256];
    float* dn0 = (float*)Als;   // aliased AFTER the last gemm
    const int tid=threadIdx.x, wid=tid>>6, lane=tid&63, lr=lane&15, lq=lane>>4;
    const int wr=wid>>2, cb=(wid&3)*64;
    const int bm = blockIdx.x*64;

    if (tid<256) W8s[tid] = a.w8col[(size_t)tid*257];
    __syncthreads();
    // dZ7 = W8[:,0] * fac7
    {
        int row = tid&63, c0 = (tid>>6)*32;
        const bf16* f7 = a.fac[7] + (size_t)(bm+row)*256 + c0;
        bf16* ah=&Ahs[row*AS+c0]; bf16* al=&Als[row*AS+c0];
        #pragma unroll
        for (int c=0;c<32;c+=8){
            bf16x8 fv = *(const bf16x8*)(f7+c);
            bf16x8 hv, lv;
            #pragma unroll
            for (int j=0;j<8;j++){
                float v = W8s[c0+c+j]*(float)fv[j];
                bf16 h=(bf16)v; hv[j]=h; lv[j]=(bf16)(v-(float)h);
            }
            *(bf16x8*)(ah+c)=hv; *(bf16x8*)(al+c)=lv;
        }
    }
    __syncthreads();

    floatx4 acc[2][4];
    auto wb_fac = [&](const bf16* fc, int fld){
        #pragma unroll
        for (int i=0;i<2;i++){
            int rbase = wr*32+i*16+lq*4;
            #pragma unroll
            for (int j=0;j<4;j++){
                int col = cb+j*16+lr;
                #pragma unroll
                for (int r=0;r<4;r++){
                    int row = rbase+r;
                    float v = acc[i][j][r] * (float)fc[(size_t)(bm+row)*fld+col];
                    bf16 h=(bf16)v;
                    Ahs[row*AS+col]=h; Als[row*AS+col]=(bf16)(v-(float)h);
                }
            }
        }
    };

    #define BLAYER(L,NKV,FC,FLD) \
        mlp_gemm<2,AS,NKV>(a.nh[L],nullptr,a.ldn[L], Ahs,Als, acc, wr,cb,lr,lq); \
        __syncthreads(); \
        wb_fac(FC,FLD); \
        __syncthreads();

    BLAYER(7,8,a.fac[6],256)
    BLAYER(6,8,a.fac[5],256)
    BLAYER(5,8,a.fac[4],256)
    // din4 -> split
    mlp_gemm<2,AS,8>(a.nh[4],nullptr,a.ldn[4], Ahs,Als, acc, wr,cb,lr,lq);
    __syncthreads();
    #pragma unroll
    for (int i=0;i<2;i++){
        int rbase = wr*32+i*16+lq*4;
        #pragma unroll
        for (int j=0;j<4;j++){
            int col = cb+j*16+lr;
            #pragma unroll
            for (int r=0;r<4;r++){
                int row = rbase+r;
                float v = acc[i][j][r]*IS2;
                if (col<217){
                    v *= (float)a.fac[3][(size_t)(bm+row)*217+col];
                    bf16 h=(bf16)v;
                    Ahs[row*AS+col]=h; Als[row*AS+col]=(bf16)(v-(float)h);
                } else {
                    detl[row][col-217]=v;
                    Ahs[row*AS+col]=(bf16)0.f; Als[row*AS+col]=(bf16)0.f;
                }
            }
        }
    }
    __syncthreads();
    BLAYER(3,7,a.fac[2],256)
    BLAYER(2,8,a.fac[1],256)
    BLAYER(1,8,a.fac[0],256)
    #undef BLAYER
    // din0 (cols<39)
    mlp_gemm<2,AS,8>(a.nh[0],nullptr,a.ldn[0], Ahs,Als, acc, wr,cb,lr,lq);
    __syncthreads();   // all waves done reading Als -> safe to alias as dn0
    #pragma unroll
    for (int i=0;i<2;i++){
        int rbase = wr*32+i*16+lq*4;
        #pragma unroll
        for (int j=0;j<4;j++){
            int col = cb+j*16+lr;
            if (col<39){
                #pragma unroll
                for (int r=0;r<4;r++) dn0[(rbase+r)*40+col] = acc[i][j][r];
            }
        }
    }
    __syncthreads();
    if (tid<64){
        int pg = a.offp + bm + tid;
        int rI = pg>>7; int sI = pg&127;
        float zv = a.zA[rI*128+sI];
        float dist = (sI<127) ? a.zA[rI*128+sI+1]-zv : 0.03125f;
        float pm = zv + 0.5f*dist;
        float px = a.ro[3*rI+0]+a.rd[3*rI+0]*pm;
        float py = a.ro[3*rI+1]+a.rd[3*rI+1]*pm;
        float pz = a.ro[3*rI+2]+a.rd[3*rI+2]*pm;
        float g0=dn0[tid*40+0]+detl[tid][0];
        float g1=dn0[tid*40+1]+detl[tid][1];
        float g2=dn0[tid*40+2]+detl[tid][2];
        float fq=1.f;
        #pragma unroll
        for (int q=0;q<6;q++){
            int base=3+6*q;
            float ds0=dn0[tid*40+base+0]+detl[tid][base+0];
            float ds1=dn0[tid*40+base+1]+detl[tid][base+1];
            float ds2=dn0[tid*40+base+2]+detl[tid][base+2];
            float dc0=dn0[tid*40+base+3]+detl[tid][base+3];
            float dc1=dn0[tid*40+base+4]+detl[tid][base+4];
            float dc2=dn0[tid*40+base+5]+detl[tid][base+5];
            g0 += fq*(__cosf(fq*px)*ds0 - __sinf(fq*px)*dc0);
            g1 += fq*(__cosf(fq*py)*ds1 - __sinf(fq*py)*dc1);
            g2 += fq*(__cosf(fq*pz)*ds2 - __sinf(fq*pz)*dc2);
            fq *= 2.f;
        }
        float dx=a.rd[3*rI],dy=a.rd[3*rI+1],dz=a.rd[3*rI+2];
        a.tcos[pg] = dx*g0+dy*g1+dz*g2;
        float nm = fmaxf(sqrtf(g0*g0+g1*g1+g2*g2), 1e-6f);
        float vals[9] = {px,py,pz,dx,dy,dz,g0/nm,g1/nm,g2/nm};
        bf16* ch = a.cinH + (size_t)(bm+tid)*272;
        bf16* cl = a.cinL + (size_t)(bm+tid)*272;
        #pragma unroll
        for (int c=0;c<9;c++){
            float v=vals[c]; bf16 h=(bf16)v;
            ch[c]=h; cl[c]=(bf16)(v-(float)h);
        }
        #pragma unroll
        for (int c=265;c<272;c++){ ch[c]=(bf16)0.f; cl[c]=(bf16)0.f; }
    }
}

// ---------- fused color MLP ----------
struct ColArgs {
    const bf16 *cinH, *cinL;
    const bf16 *w0h,*w0l; int ld0; const float* b0;
    const bf16 *w1h,*w1l; const float* b1;
    const float* w2; const float* b2;
    float* rgb;
};

__global__ __launch_bounds__(512,4) void k_col(ColArgs a)
{
    __shared__ bf16 Ahs[64*AS2], Als[64*AS2];
    __shared__ float W2s[256*3];
    const int tid=threadIdx.x, wid=tid>>6, lane=tid&63, lr=lane&15, lq=lane>>4;
    const int wr=wid>>2, cb=(wid&3)*64;
    const int bm = blockIdx.x*64;

    if (tid<256){ W2s[tid*3]=a.w2[tid*3]; W2s[tid*3+1]=a.w2[tid*3+1]; W2s[tid*3+2]=a.w2[tid*3+2]; }
    // stage cin (hi/lo) into LDS: 8 parts = 2 planes x 4 col-chunks of 72 (last 56 + 24 zero-pad)
    {
        int row = tid&63, sel = tid>>6;
        int plane = sel>>2, c0 = (sel&3)*72;
        const bf16* src = plane? a.cinL : a.cinH;
        bf16* dst = plane? Als : Ahs;
        const bf16* s = src + (size_t)(bm+row)*272 + c0;
        bf16* d = dst + row*AS2 + c0;
        int nv = (c0==216)? 7 : 9;
        for (int v=0;v<nv;v++) *(bf16x8*)(d+v*8) = *(const bf16x8*)(s+v*8);
        if ((sel&3)==3){
            bf16x8 z = {};
            bf16* zd = dst + row*AS2 + 272;
            #pragma unroll
            for (int v=0;v<3;v++) *(bf16x8*)(zd+v*8) = z;
        }
    }
    __syncthreads();

    floatx4 acc[2][4];
    auto wb_relu = [&](const float* bias){
        #pragma unroll
        for (int i=0;i<2;i++){
            int rbase = wr*32+i*16+lq*4;
            #pragma unroll
            for (int j=0;j<4;j++){
                int col = cb+j*16+lr;
                float bv = bias[col];
                #pragma unroll
                for (int r=0;r<4;r++){
                    int row = rbase+r;
                    float v = fmaxf(acc[i][j][r]+bv, 0.f);
                    bf16 h=(bf16)v;
                    Ahs[row*AS2+col]=h; Als[row*AS2+col]=(bf16)(v-(float)h);
                }
            }
        }
    };
    mlp_gemm<3,AS2,9>(a.w0h,a.w0l,a.ld0, Ahs,Als, acc, wr,cb,lr,lq);
    __syncthreads();
    wb_relu(a.b0);
    __syncthreads();
    mlp_gemm<3,AS2,8>(a.w1h,a.w1l,256, Ahs,Als, acc, wr,cb,lr,lq);
    __syncthreads();
    wb_relu(a.b1);
    __syncthreads();
    // rgb = sigmoid(h @ cw2 + cb2)   (8 lanes per row)
    {
        int row = wid*8 + (lane>>3);
        int kc  = (lane&7)*32;
        const bf16* ah=&Ahs[row*AS2+kc]; const bf16* al=&Als[row*AS2+kc];
        float s0=0.f,s1=0.f,s2=0.f;
        #pragma unroll
        for (int c=0;c<4;c++){
            bf16x8 vh=*(const bf16x8*)(ah+c*8), vl=*(const bf16x8*)(al+c*8);
            #pragma unroll
            for (int j=0;j<8;j++){
                float fv = (float)vh[j]+(float)vl[j];
                int k = kc+c*8+j;
                s0 += fv*W2s[k*3]; s1 += fv*W2s[k*3+1]; s2 += fv*W2s[k*3+2];
            }
        }
        #pragma unroll
        for (int m=1;m<8;m<<=1){
            s0 += __shfl_xor(s0,m,64); s1 += __shfl_xor(s1,m,64); s2 += __shfl_xor(s2,m,64);
        }
        if ((lane&7)==0){
            float* o = a.rgb + (size_t)(bm+row)*3;
            o[0]=sigm(s0+a.b2[0]); o[1]=sigm(s1+a.b2[1]); o[2]=sigm(s2+a.b2[2]);
        }
    }
}

// ---------- weight conversion ----------
struct ConvDesc { const float* src; bf16 *th, *tl, *nh; int K, N, ldt, ldn; };
struct ConvArgs { ConvDesc d[11]; };
__global__ void k_conv(ConvArgs a){
    ConvDesc cd = a.d[blockIdx.y];
    int idx = blockIdx.x*256+threadIdx.x;
    if (idx >= cd.K*cd.N) return;
    int k = idx / cd.N, n = idx - k*cd.N;
    float v = cd.src[idx];
    bf16 h = (bf16)v;
    cd.th[(size_t)n*cd.ldt + k] = h;
    cd.tl[(size_t)n*cd.ldt + k] = (bf16)(v - (float)h);
    if (cd.nh) cd.nh[(size_t)k*cd.ldn + n] = h;
}

// ---------- small kernels ----------
__global__ void k_ray_setup(const float* __restrict__ o, const float* __restrict__ d,
                            float* __restrict__ z)
{
    int r = blockIdx.x; int i = threadIdx.x;
    float ox=o[3*r],oy=o[3*r+1],oz=o[3*r+2];
    float dx=d[3*r],dy=d[3*r+1],dz=d[3*r+2];
    float a = dx*dx+dy*dy+dz*dz;
    float b = 2.f*(ox*dx+oy*dy+oz*dz);
    float mid = -b/(2.f*a);
    float nearv = fmaxf(mid-1.f, 0.05f);
    float farv = mid+1.f;
    z[r*128+i] = nearv + (farv-nearv)*((float)i/63.f);
}

__global__ void k_upsample(const float* __restrict__ o, const float* __restrict__ d,
                           const float* __restrict__ z, const float* __restrict__ sdf,
                           int S, float inv_s, float* __restrict__ new_z)
{
    int r = blockIdx.x*64+threadIdx.x; if (r>=NR) return;
    const float* zr = z + r*128;
    const float* sr = sdf + r*128;
    float ox=o[3*r],oy=o[3*r+1],oz=o[3*r+2];
    float dx=d[3*r],dy=d[3*r+1],dz=d[3*r+2];
    float w[128];
    float cdf[129];
    float wsum=0.f, T=1.f, raw_prev=0.f;
    float z0 = zr[0];
    float px=ox+dx*z0, py=oy+dy*z0, pz=oz+dz*z0;
    float r0 = sqrtf(px*px+py*py+pz*pz);
    for (int i=0;i<S-1;i++){
        float z1 = zr[i+1];
        float qx=ox+dx*z1, qy=oy+dy*z1, qz=oz+dz*z1;
        float r1 = sqrtf(qx*qx+qy*qy+qz*qz);
        bool inside = (r0<1.f)||(r1<1.f);
        float s0=sr[i], s1=sr[i+1];
        float zc = zr[i];
        float mid_sdf = 0.5f*(s0+s1);
        float raw = (s1-s0)/(z1-zc+1e-5f);
        float cv = fminf(raw, (i==0)?0.f:raw_prev);
        raw_prev = raw;
        cv = fminf(fmaxf(cv,-1000.f),0.f);
        if (!inside) cv = 0.f;
        float dist = z1-zc;
        float pe = mid_sdf - cv*dist*0.5f;
        float ne = mid_sdf + cv*dist*0.5f;
        float pc = sigm(pe*inv_s), nc = sigm(ne*inv_s);
        float alpha = (pc-nc+1e-5f)/(pc+1e-5f);
        float wi = alpha*T;
        T *= (1.f-alpha+1e-7f);
        w[i] = wi + 1e-5f;
        wsum += w[i];
        r0 = r1;
    }
    cdf[0]=0.f;
    float c=0.f;
    for (int i=0;i<S-1;i++){ c += w[i]/wsum; cdf[i+1]=c; }
    for (int j=0;j<16;j++){
        float u = 0.03125f + 0.0625f*(float)j;
        int lo=0, hi=S;
        while (lo<hi){ int m=(lo+hi)>>1; if (cdf[m]<=u) lo=m+1; else hi=m; }
        int idx = lo;
        int below = idx-1; if (below<0) below=0; if (below>S-1) below=S-1;
        int above = idx;   if (above>S-1) above=S-1;
        float c0=cdf[below], c1=cdf[above];
        float b0=zr[below], b1=zr[above];
        float dn = c1-c0; if (dn<1e-5f) dn=1.f;
        new_z[r*16+j] = b0 + (u-c0)/dn*(b1-b0);
    }
}

__global__ void k_merge(const float* __restrict__ zin, const float* __restrict__ sin_,
                        const float* __restrict__ nz, const float* __restrict__ nsdf,
                        int S, float* __restrict__ zout, float* __restrict__ sout)
{
    int r = blockIdx.x*64+threadIdx.x; if (r>=NR) return;
    const float* az = zin + r*128; const float* as = sin_ + r*128;
    const float* bz = nz + r*16;   const float* bs = nsdf + r*16;
    int i=0, j=0;
    for (int k=0;k<S+16;k++){
        bool takeA = (j>=16) || (i<S && az[i] <= bz[j]);
        if (takeA){ zout[r*128+k]=az[i]; sout[r*128+k]=as[i]; i++; }
        else      { zout[r*128+k]=bz[j]; sout[r*128+k]=bs[j]; j++; }
    }
}

__global__ void k_composite(const float* __restrict__ z, const float* __restrict__ sdfv,
                            const float* __restrict__ tcos, const float* __restrict__ rgbs,
                            const float* __restrict__ var, float* __restrict__ out)
{
    int r = blockIdx.x*64+threadIdx.x; if (r>=NR) return;
    float inv_s = expf(var[0]*10.f);
    inv_s = fminf(fmaxf(inv_s,1e-6f),1e6f);
    float T=1.f, c0=0.f, c1=0.f, c2=0.f;
    for (int sI=0;sI<128;sI++){
        float zv = z[r*128+sI];
        float dist = (sI<127)? z[r*128+sI+1]-zv : 0.03125f;
        float sd = sdfv[r*128+sI];
        float ic = fminf(tcos[r*128+sI], 0.f);
        float ep = sd - ic*dist*0.5f, en = sd + ic*dist*0.5f;
        float pc = sigm(ep*inv_s), nc = sigm(en*inv_s);
        float al = (pc-nc+1e-5f)/(pc+1e-5f);
        al = fminf(fmaxf(al,0.f),1.f);
        float wgt = al*T;
        T *= (1.f-al+1e-7f);
        c0 += wgt*rgbs[(size_t)(r*128+sI)*3+0];
        c1 += wgt*rgbs[(size_t)(r*128+sI)*3+1];
        c2 += wgt*rgbs[(size_t)(r*128+sI)*3+2];
    }
    out[3*r+0]=c0; out[3*r+1]=c1; out[3*r+2]=c2;
}

// ---------- host ----------
static inline size_t ru8(size_t x){ return (x+7)&~(size_t)7; }

extern "C" void kernel_launch(void* const* d_in, const int* in_sizes, int n_in,
                              void* d_out, int out_size, void* d_ws, size_t ws_size,
                              hipStream_t stream)
{
    const float* rays_o = (const float*)d_in[0];
    const float* rays_d = (const float*)d_in[1];
    const float* sw[9]; const float* sb[9];
    for (int l=0;l<9;l++){ sw[l]=(const float*)d_in[2+2*l]; sb[l]=(const float*)d_in[3+2*l]; }
    const float* cw0=(const float*)d_in[20]; const float* cb0=(const float*)d_in[21];
    const float* cw1=(const float*)d_in[22]; const float* cb1=(const float*)d_in[23];
    const float* cw2=(const float*)d_in[24]; const float* cb2=(const float*)d_in[25];
    const float* varp=(const float*)d_in[26];
    float* out = (float*)d_out;
    float* f = (float*)d_ws;
    size_t nf = ws_size/sizeof(float);

    size_t off = 0;
    auto AF = [&](size_t n){ float* p = f+off; off += n; return p; };
    float* zA   = AF(NR*128);
    float* zB   = AF(NR*128);
    float* sA   = AF(NR*128);
    float* sB   = AF(NR*128);
    float* nzb  = AF(NR*16);
    float* nsb  = AF(NR*16);
    float* sdfF = AF(NR*128);
    float* tcos = AF(NR*128);
    float* rgbs = AF((size_t)NR*128*3);

    off = (off+3)&~(size_t)3;   // 16B-align the bf16 pool
    bf16* wb = (bf16*)(f+off);
    size_t wboff = 0;
    auto AB = [&](size_t n){ n = ru8(n)+32; bf16* p = wb+wboff; wboff += n; return p; };

    const int inD[9]  = {39,256,256,256,256,256,256,256,256};
    const int outD[9] = {256,256,256,217,256,256,256,256,257};
    const bf16 *tH[11], *tL[11]; int ldt[11];
    const bf16 *nH[8]; int ldn_[8];
    ConvArgs ca;
    for (int l=0;l<9;l++){
        int K=inD[l], N=outD[l];
        int ld = (int)ru8(K);
        bf16* th = AB((size_t)N*ld);
        bf16* tl = AB((size_t)N*ld);
        bf16* nh = nullptr; int ldn = 0;
        if (l<8){ ldn = (int)ru8(N); nh = AB((size_t)K*ldn); nH[l]=nh; ldn_[l]=ldn; }
        tH[l]=th; tL[l]=tl; ldt[l]=ld;
        ca.d[l] = ConvDesc{ sw[l], th, tl, nh, K, N, ld, ldn };
    }
    {
        int K=265, N=256, ld=(int)ru8(K); // 272
        bf16* th = AB((size_t)N*ld); bf16* tl = AB((size_t)N*ld);
        tH[9]=th; tL[9]=tl; ldt[9]=ld;
        ca.d[9] = ConvDesc{ cw0, th, tl, nullptr, K, N, ld, 0 };
        K=256; N=256; ld=256;
        bf16* th1 = AB((size_t)N*ld); bf16* tl1 = AB((size_t)N*ld);
        tH[10]=th1; tL[10]=tl1; ldt[10]=ld;
        ca.d[10] = ConvDesc{ cw1, th1, tl1, nullptr, K, N, ld, 0 };
    }
    off += (wboff+1)/2;
    off = (off+3)&~(size_t)3;

    // chunk region (fac planes + cin planes only)
    size_t avail = (nf > off) ? nf - off : 0;
    int CHF = 131072;
    while (CHF > 1024 && (size_t)CHF*1280 > avail) CHF >>= 1;

    bf16* cb2_ = (bf16*)(f+off);
    size_t bo2 = 0;
    auto B3 = [&](size_t n){ n=ru8(n); bf16* p=cb2_+bo2; bo2+=n; return p; };
    bf16* facP[8];
    for (int l=0;l<8;l++){
        int ld = (l==3)? 217 : 256;
        facP[l] = B3((size_t)CHF*ld);
    }
    bf16* cinH = B3((size_t)CHF*272);
    bf16* cinL = B3((size_t)CHF*272);

    // ---- weight conversion ----
    k_conv<<<dim3(266,11),256,0,stream>>>(ca);
    // ---- rays + base z ----
    k_ray_setup<<<NR,64,0,stream>>>(rays_o, rays_d, zA);

    FwdArgs fa{};
    for (int l=0;l<9;l++){ fa.wh[l]=tH[l]; fa.wl[l]=tL[l]; fa.wld[l]=ldt[l]; fa.bias[l]=sb[l]; }
    fa.w8col = sw[8]; fa.ro = rays_o; fa.rd = rays_d;

    // ---- sampling: base (64 samples/ray) ----
    {
        FwdArgs s = fa;
        s.zbuf=zA; s.zper=64; s.zstr=128; s.pmode=0;
        s.sdfo = sA; s.soff=0; s.sper=64; s.sstr=128;
        k_fwd<0><<<65536/64,512,0,stream>>>(s);
    }
    // ---- 4 up-sample steps ----
    for (int it=0; it<4; it++){
        int S = 64 + 16*it;
        float* zsrc = (it&1)? zB : zA;  float* ssrc = (it&1)? sB : sA;
        float* zdst = (it&1)? zA : zB;  float* sdst = (it&1)? sA : sB;
        float inv_s = 64.f * (float)(1<<it);
        k_upsample<<<NR/64,64,0,stream>>>(rays_o, rays_d, zsrc, ssrc, S, inv_s, nzb);
        FwdArgs s = fa;
        s.zbuf=nzb; s.zper=16; s.zstr=16; s.pmode=0;
        s.sdfo = nsb; s.soff=0; s.sper=16; s.sstr=16;
        k_fwd<0><<<(NR*16)/64,512,0,stream>>>(s);
        k_merge<<<NR/64,64,0,stream>>>(zsrc, ssrc, nzb, nsb, S, zdst, sdst);
    }
    // final z in zA

    // ---- final phase ----
    for (int offp=0; offp<NR*128; offp+=CHF){
        int n = CHF;
        FwdArgs s = fa;
        s.zbuf=zA; s.pmode=1;
        s.sdfo = sdfF; s.soff=offp; s.sper=1; s.sstr=1;
        s.cinH=cinH; s.cinL=cinL;
        for (int l=0;l<8;l++) s.fac[l]=facP[l];
        k_fwd<1><<<n/64,512,0,stream>>>(s);

        BwdArgs b{};
        for (int l=0;l<8;l++){ b.nh[l]=nH[l]; b.ldn[l]=ldn_[l]; b.fac[l]=facP[l]; }
        b.w8col = sw[8]; b.zA = zA; b.ro = rays_o; b.rd = rays_d;
        b.cinH=cinH; b.cinL=cinL; b.tcos=tcos; b.offp=offp;
        k_bwd<<<n/64,512,0,stream>>>(b);

        ColArgs c{};
        c.cinH=cinH; c.cinL=cinL;
        c.w0h=tH[9]; c.w0l=tL[9]; c.ld0=ldt[9]; c.b0=cb0;
        c.w1h=tH[10]; c.w1l=tL[10]; c.b1=cb1;
        c.w2=cw2; c.b2=cb2; c.rgb = rgbs + (size_t)offp*3;
        k_col<<<n/64,512,0,stream>>>(c);
    }
    k_composite<<<NR/64,64,0,stream>>>(zA, sdfF, tcos, rgbs, varp, out);
}